// Round 18
// baseline (663.854 us; speedup 1.0000x reference)
//
#include <hip/hip_runtime.h>
#include <math.h>

#define BB 4
#define TT 4096
#define DD 768
#define SS 1024
#define S2 2048
#define KTOP 8
#define RWEIGHT 0.1f
#define TAU 2e-4f
#define AMB_CAP 256

typedef __attribute__((ext_vector_type(8))) _Float16 f16x8;
typedef __attribute__((ext_vector_type(4))) float f32x4;
typedef _Float16 f16;

// Fragment-plane addressing: plane[(row>>4, k>>5) block][(row&15)+((k>>3)&3)*16][k&7]
// Lane l's f16x8 fragment for block (rb,kb) sits at ((rb*24+kb)*512 + l*8).
__device__ __forceinline__ size_t fragoff(int row, int k) {
    return ((size_t)(row >> 4) * 24 + (k >> 5)) * 512 +
           (((row & 15) + (((k >> 3) & 3) << 4)) << 3) + (k & 7);
}

// ---------------------------------------------------------------------------
__global__ __launch_bounds__(256) void build_pooled_all(
    const float* __restrict__ x, float* __restrict__ slots)
{
    int i = blockIdx.x * 256 + threadIdx.x;     // over B*S*D = 3145728
    int s2 = i / DD;
    int d = i - s2 * DD;
    int b = s2 >> 10, s = s2 & 1023;
    const float* xb = x + (size_t)b * TT * DD + (size_t)(4 * s) * DD + d;
    slots[i] = 0.25f * (xb[0] + xb[DD] + xb[2 * DD] + xb[3 * DD]);
}

// ---------------------------------------------------------------------------
// transpose_split: weight planes in FRAGMENT layout + f32 WkT (fixB).
// ---------------------------------------------------------------------------
__global__ __launch_bounds__(256) void transpose_split(
    const float* __restrict__ W0, const float* __restrict__ W1,
    const float* __restrict__ W2, const float* __restrict__ W3,
    f16* __restrict__ WQh, f16* __restrict__ WQm,
    f16* __restrict__ WKh, f16* __restrict__ WKm,
    f16* __restrict__ WVh, f16* __restrict__ WPh,
    float* __restrict__ WkT32)
{
    const int z = blockIdx.z;
    const float* W = (z == 0) ? W0 : (z == 1) ? W1 : (z == 2) ? W2 : W3;
    __shared__ float t[32][33];
    int bx = blockIdx.x * 32, by = blockIdx.y * 32;
    int lx = threadIdx.x & 31, ly = threadIdx.x >> 5;
#pragma unroll
    for (int r = 0; r < 32; r += 8)
        t[ly + r][lx] = W[(size_t)(bx + ly + r) * 768 + by + lx];
    __syncthreads();
#pragma unroll
    for (int r = 0; r < 32; r += 8) {
        float w = t[lx][ly + r];
        int n = by + ly + r, k = bx + lx;        // W^T[n][k]
        size_t fo = fragoff(n, k);
        f16 h = (f16)w;
        if (z == 0) { WQh[fo] = h; WQm[fo] = (f16)(w - (float)h); }
        else if (z == 1) { WKh[fo] = h; WKm[fo] = (f16)(w - (float)h);
                           WkT32[(size_t)n * 768 + k] = w; }
        else if (z == 2) { WVh[fo] = h; }
        else { WPh[fo] = h; }
    }
}

__global__ void zeroN(int* p) { p[threadIdx.x] = 0; }

// ---------------------------------------------------------------------------
// A-staging swizzle (verified r8): p(c,r)=c^(r&3)^((r>>2)&1);
// csw = ((l>>4)^(l&3)^((l>>2)&1))*8.
// ---------------------------------------------------------------------------
// 3-pass split producer (q,k): A f32 staged+split, B frag-direct,
// output h/m planes in FRAGMENT layout.
__device__ __forceinline__ void tile_split_prod(
    const float* __restrict__ A, int arow0,
    const f16* __restrict__ BhF, const f16* __restrict__ BmF, int bncol,
    const float* __restrict__ bias,
    f16* __restrict__ ChF, f16* __restrict__ CmF, int crow0,
    f16* LAh, f16* LAm)
{
    const int tid = threadIdx.x;
    const int lane = tid & 63;
    const int wc = (tid >> 6) & 1;
    const int wr = (tid >> 7) & 1;
    const int srow = tid >> 1, c0 = tid & 1;
    const int p0 = c0 ^ (srow & 3) ^ ((srow >> 2) & 1);
    const int wo0 = srow * 32 + p0 * 8, wo1 = wo0 ^ 16;
    const int csw = (((lane >> 4) ^ (lane & 3) ^ ((lane >> 2) & 1)) * 8);

    f32x4 acc[4][4];
#pragma unroll
    for (int i = 0; i < 4; ++i)
#pragma unroll
        for (int j = 0; j < 4; ++j) acc[i][j] = (f32x4){0.f, 0.f, 0.f, 0.f};

    const float* pa = A + (size_t)(arow0 + srow) * 768 + c0 * 8;
    const int rbB0 = bncol / 16 + wc * 4;

    float4 a0 = *(const float4*)(pa);
    float4 a1 = *(const float4*)(pa + 4);
    float4 a2 = *(const float4*)(pa + 16);
    float4 a3 = *(const float4*)(pa + 20);

    for (int kb = 0; kb < 24; ++kb) {
        __syncthreads();
        {
            float av[16] = {a0.x, a0.y, a0.z, a0.w, a1.x, a1.y, a1.z, a1.w,
                            a2.x, a2.y, a2.z, a2.w, a3.x, a3.y, a3.z, a3.w};
            f16x8 h, m;
#pragma unroll
            for (int j = 0; j < 8; ++j) {
                f16 hh = (f16)av[j]; h[j] = hh; m[j] = (f16)(av[j] - (float)hh);
            }
            *(f16x8*)&LAh[wo0] = h; *(f16x8*)&LAm[wo0] = m;
#pragma unroll
            for (int j = 0; j < 8; ++j) {
                f16 hh = (f16)av[j + 8]; h[j] = hh; m[j] = (f16)(av[j + 8] - (float)hh);
            }
            *(f16x8*)&LAh[wo1] = h; *(f16x8*)&LAm[wo1] = m;
        }
        __syncthreads();

        if (kb + 1 < 24) {                    // prefetch next A k-step
            int k0 = (kb + 1) * 32;
            a0 = *(const float4*)(pa + k0);
            a1 = *(const float4*)(pa + k0 + 4);
            a2 = *(const float4*)(pa + k0 + 16);
            a3 = *(const float4*)(pa + k0 + 20);
        }

        f16x8 fbh[4], fbm[4];
#pragma unroll
        for (int ni = 0; ni < 4; ++ni) {
            size_t off = ((size_t)(rbB0 + ni) * 24 + kb) * 512 + lane * 8;
            fbh[ni] = *(const f16x8*)&BhF[off];
            fbm[ni] = *(const f16x8*)&BmF[off];
        }
        f16x8 fah[4], fam[4];
#pragma unroll
        for (int mi = 0; mi < 4; ++mi) {
            int off = (wr * 64 + mi * 16 + (lane & 15)) * 32 + csw;
            fah[mi] = *(const f16x8*)&LAh[off];
            fam[mi] = *(const f16x8*)&LAm[off];
        }
#pragma unroll
        for (int mi = 0; mi < 4; ++mi)
#pragma unroll
            for (int ni = 0; ni < 4; ++ni) {
                acc[mi][ni] = __builtin_amdgcn_mfma_f32_16x16x32_f16(
                    fah[mi], fbh[ni], acc[mi][ni], 0, 0, 0);
                acc[mi][ni] = __builtin_amdgcn_mfma_f32_16x16x32_f16(
                    fah[mi], fbm[ni], acc[mi][ni], 0, 0, 0);
                acc[mi][ni] = __builtin_amdgcn_mfma_f32_16x16x32_f16(
                    fam[mi], fbh[ni], acc[mi][ni], 0, 0, 0);
            }
    }

    const int orow0 = wr * 64 + (lane >> 4) * 4;
    const int ocol0 = wc * 64 + (lane & 15);
#pragma unroll
    for (int mi = 0; mi < 4; ++mi)
#pragma unroll
        for (int ni = 0; ni < 4; ++ni) {
            int kk = bncol + ocol0 + ni * 16;
            float badd = bias[kk];
            int rbase = crow0 + orow0 + mi * 16;
#pragma unroll
            for (int r = 0; r < 4; ++r) {
                float val = acc[mi][ni][r] + badd;
                f16 h = (f16)val;
                size_t fo = fragoff(rbase + r, kk);
                ChF[fo] = h;
                CmF[fo] = (f16)(val - (float)h);
            }
        }
}

// 1-pass producer (v): A f32 staged, B frag-direct, output v16 ROW-major.
__device__ __forceinline__ void tile_1p_prod(
    const float* __restrict__ A, int arow0,
    const f16* __restrict__ BhF, int bncol,
    const float* __restrict__ bias,
    f16* __restrict__ Co, int crow0, f16* LA)
{
    const int tid = threadIdx.x;
    const int lane = tid & 63;
    const int wc = (tid >> 6) & 1;
    const int wr = (tid >> 7) & 1;
    const int srow = tid >> 1, c0 = tid & 1;
    const int p0 = c0 ^ (srow & 3) ^ ((srow >> 2) & 1);
    const int wo0 = srow * 32 + p0 * 8, wo1 = wo0 ^ 16;
    const int csw = (((lane >> 4) ^ (lane & 3) ^ ((lane >> 2) & 1)) * 8);

    f32x4 acc[4][4];
#pragma unroll
    for (int i = 0; i < 4; ++i)
#pragma unroll
        for (int j = 0; j < 4; ++j) acc[i][j] = (f32x4){0.f, 0.f, 0.f, 0.f};

    const float* pa = A + (size_t)(arow0 + srow) * 768 + c0 * 8;
    const int rbB0 = bncol / 16 + wc * 4;

    float4 a0 = *(const float4*)(pa);
    float4 a1 = *(const float4*)(pa + 4);
    float4 a2 = *(const float4*)(pa + 16);
    float4 a3 = *(const float4*)(pa + 20);

    for (int kb = 0; kb < 24; ++kb) {
        __syncthreads();
        {
            f16x8 h;
            h[0] = (f16)a0.x; h[1] = (f16)a0.y; h[2] = (f16)a0.z; h[3] = (f16)a0.w;
            h[4] = (f16)a1.x; h[5] = (f16)a1.y; h[6] = (f16)a1.z; h[7] = (f16)a1.w;
            *(f16x8*)&LA[wo0] = h;
            h[0] = (f16)a2.x; h[1] = (f16)a2.y; h[2] = (f16)a2.z; h[3] = (f16)a2.w;
            h[4] = (f16)a3.x; h[5] = (f16)a3.y; h[6] = (f16)a3.z; h[7] = (f16)a3.w;
            *(f16x8*)&LA[wo1] = h;
        }
        __syncthreads();

        if (kb + 1 < 24) {
            int k0 = (kb + 1) * 32;
            a0 = *(const float4*)(pa + k0);
            a1 = *(const float4*)(pa + k0 + 4);
            a2 = *(const float4*)(pa + k0 + 16);
            a3 = *(const float4*)(pa + k0 + 20);
        }

        f16x8 fbh[4];
#pragma unroll
        for (int ni = 0; ni < 4; ++ni)
            fbh[ni] = *(const f16x8*)&BhF[((size_t)(rbB0 + ni) * 24 + kb) * 512 + lane * 8];
        f16x8 fah[4];
#pragma unroll
        for (int mi = 0; mi < 4; ++mi)
            fah[mi] = *(const f16x8*)&LA[(wr * 64 + mi * 16 + (lane & 15)) * 32 + csw];
#pragma unroll
        for (int mi = 0; mi < 4; ++mi)
#pragma unroll
            for (int ni = 0; ni < 4; ++ni)
                acc[mi][ni] = __builtin_amdgcn_mfma_f32_16x16x32_f16(
                    fah[mi], fbh[ni], acc[mi][ni], 0, 0, 0);
    }

    const int orow0 = wr * 64 + (lane >> 4) * 4;
    const int ocol0 = wc * 64 + (lane & 15);
#pragma unroll
    for (int mi = 0; mi < 4; ++mi)
#pragma unroll
        for (int ni = 0; ni < 4; ++ni) {
            size_t col = (size_t)bncol + ocol0 + ni * 16;
            float badd = bias[col];
            size_t rbase = (size_t)crow0 + orow0 + mi * 16;
#pragma unroll
            for (int r = 0; r < 4; ++r)
                Co[(rbase + r) * 768 + col] = (f16)(acc[mi][ni][r] + badd);
        }
}

// proj: A retr-frag, B WPh-frag, NO LDS. f32 out scaled by RWEIGHT.
__device__ __forceinline__ void tile_proj_frag(
    const f16* __restrict__ AF, int arow0,
    const f16* __restrict__ BhF, int bncol,
    const float* __restrict__ bias,
    float* __restrict__ Co, int crow0)
{
    const int tid = threadIdx.x;
    const int lane = tid & 63;
    const int wc = (tid >> 6) & 1;
    const int wr = (tid >> 7) & 1;

    f32x4 acc[4][4];
#pragma unroll
    for (int i = 0; i < 4; ++i)
#pragma unroll
        for (int j = 0; j < 4; ++j) acc[i][j] = (f32x4){0.f, 0.f, 0.f, 0.f};

    const int rbA0 = arow0 / 16 + wr * 4;
    const int rbB0 = bncol / 16 + wc * 4;

    for (int kb = 0; kb < 24; ++kb) {
        f16x8 fah[4], fbh[4];
#pragma unroll
        for (int mi = 0; mi < 4; ++mi)
            fah[mi] = *(const f16x8*)&AF[((size_t)(rbA0 + mi) * 24 + kb) * 512 + lane * 8];
#pragma unroll
        for (int ni = 0; ni < 4; ++ni)
            fbh[ni] = *(const f16x8*)&BhF[((size_t)(rbB0 + ni) * 24 + kb) * 512 + lane * 8];
#pragma unroll
        for (int mi = 0; mi < 4; ++mi)
#pragma unroll
            for (int ni = 0; ni < 4; ++ni)
                acc[mi][ni] = __builtin_amdgcn_mfma_f32_16x16x32_f16(
                    fah[mi], fbh[ni], acc[mi][ni], 0, 0, 0);
    }

    const int orow0 = wr * 64 + (lane >> 4) * 4;
    const int ocol0 = wc * 64 + (lane & 15);
#pragma unroll
    for (int mi = 0; mi < 4; ++mi)
#pragma unroll
        for (int ni = 0; ni < 4; ++ni) {
            size_t col = (size_t)bncol + ocol0 + ni * 16;
            float badd = RWEIGHT * bias[col];
            size_t rbase = (size_t)crow0 + orow0 + mi * 16;
#pragma unroll
            for (int r = 0; r < 4; ++r)
                Co[(rbase + r) * 768 + col] = RWEIGHT * acc[mi][ni][r] + badd;
        }
}

// 3-pass scores, all operands frag-direct, NO LDS / NO barriers.
__device__ __forceinline__ void tile_scores_frag(
    const f16* __restrict__ qhF, const f16* __restrict__ qmF, int arow0,
    const f16* __restrict__ khF, const f16* __restrict__ kmF, int bncol,
    float* __restrict__ C, float alpha)
{
    const int tid = threadIdx.x;
    const int lane = tid & 63;
    const int wc = (tid >> 6) & 1;
    const int wr = (tid >> 7) & 1;

    f32x4 acc[4][4];
#pragma unroll
    for (int i = 0; i < 4; ++i)
#pragma unroll
        for (int j = 0; j < 4; ++j) acc[i][j] = (f32x4){0.f, 0.f, 0.f, 0.f};

    const int rbA0 = arow0 / 16 + wr * 4;
    const int rbB0 = bncol / 16 + wc * 4;

    for (int kb = 0; kb < 24; ++kb) {
        f16x8 fah[4], fam[4], fbh[4], fbm[4];
#pragma unroll
        for (int mi = 0; mi < 4; ++mi) {
            size_t off = ((size_t)(rbA0 + mi) * 24 + kb) * 512 + lane * 8;
            fah[mi] = *(const f16x8*)&qhF[off];
            fam[mi] = *(const f16x8*)&qmF[off];
        }
#pragma unroll
        for (int ni = 0; ni < 4; ++ni) {
            size_t off = ((size_t)(rbB0 + ni) * 24 + kb) * 512 + lane * 8;
            fbh[ni] = *(const f16x8*)&khF[off];
            fbm[ni] = *(const f16x8*)&kmF[off];
        }
#pragma unroll
        for (int mi = 0; mi < 4; ++mi)
#pragma unroll
            for (int ni = 0; ni < 4; ++ni) {
                acc[mi][ni] = __builtin_amdgcn_mfma_f32_16x16x32_f16(
                    fah[mi], fbh[ni], acc[mi][ni], 0, 0, 0);
                acc[mi][ni] = __builtin_amdgcn_mfma_f32_16x16x32_f16(
                    fah[mi], fbm[ni], acc[mi][ni], 0, 0, 0);
                acc[mi][ni] = __builtin_amdgcn_mfma_f32_16x16x32_f16(
                    fam[mi], fbh[ni], acc[mi][ni], 0, 0, 0);
            }
    }

    const int orow0 = wr * 64 + (lane >> 4) * 4;
    const int ocol0 = wc * 64 + (lane & 15);
#pragma unroll
    for (int mi = 0; mi < 4; ++mi)
#pragma unroll
        for (int ni = 0; ni < 4; ++ni) {
            size_t col = (size_t)bncol + ocol0 + ni * 16;
            size_t rbase = (size_t)arow0 + orow0 + mi * 16;
#pragma unroll
            for (int r = 0; r < 4; ++r)
                C[(rbase + r) * S2 + col] = alpha * acc[mi][ni][r];
        }
}

// ---------------------------------------------------------------------------
// megaSelProd: [q tiles | k tiles | v tiles | select rows of prev batch]
// ---------------------------------------------------------------------------
__global__ __launch_bounds__(256) void megaSelProd(
    int nSel, const float* __restrict__ scores, const f16* __restrict__ v16r,
    f16* __restrict__ retrW, int gbase,
    int* __restrict__ ambc, int* __restrict__ ambgrow, int* __restrict__ cand,
    float* __restrict__ oldw, f16* __restrict__ vsave,
    int hasQ, int hasKV, int doPm,
    const float* __restrict__ xq, const float* __restrict__ slots_b,
    const float* __restrict__ pm,
    const f16* __restrict__ WQh, const f16* __restrict__ WQm,
    const f16* __restrict__ WKh, const f16* __restrict__ WKm,
    const f16* __restrict__ WVh,
    const float* __restrict__ bq, const float* __restrict__ bk,
    const float* __restrict__ bv,
    f16* __restrict__ qh, f16* __restrict__ qm,
    f16* __restrict__ kh, f16* __restrict__ km,
    f16* __restrict__ v16w, f16* __restrict__ v16w2)
{
    __shared__ f16 LAh[4096], LAm[4096];
    int t = blockIdx.x;

    if (hasQ) {
        if (t < 192) {
            tile_split_prod(xq, (t / 6) * 128, WQh, WQm, (t % 6) * 128, bq,
                            qh, qm, (t / 6) * 128, LAh, LAm);
            return;
        }
        t -= 192;
    }
    if (hasKV) {
        if (t < 48) {
            tile_split_prod(slots_b, (t / 6) * 128, WKh, WKm, (t % 6) * 128, bk,
                            kh, km, (t / 6) * 128, LAh, LAm);
            return;
        }
        t -= 48;
        if (doPm) {
            if (t < 48) {
                tile_split_prod(pm, (t / 6) * 128, WKh, WKm, (t % 6) * 128, bk,
                                kh, km, 1024 + (t / 6) * 128, LAh, LAm);
                return;
            }
            t -= 48;
        }
        if (t < 48) {
            tile_1p_prod(slots_b, (t / 6) * 128, WVh, (t % 6) * 128, bv,
                         v16w, (t / 6) * 128, LAh);
            return;
        }
        t -= 48;
        if (doPm) {
            if (t < 48) {
                tile_1p_prod(pm, (t / 6) * 128, WVh, (t % 6) * 128, bv,
                             v16w, 1024 + (t / 6) * 128, LAh);
                return;
            }
            t -= 48;
            if (t < 48) {
                tile_1p_prod(pm, (t / 6) * 128, WVh, (t % 6) * 128, bv,
                             v16w2, 1024 + (t / 6) * 128, LAh);
                return;
            }
            t -= 48;
        }
    }
    if (t >= nSel) return;

    // ----- select_combine: one wave per row; retr written in FRAG layout ---
    const int lane = threadIdx.x & 63;
    const int wave = threadIdx.x >> 6;
    const int row = t * 4 + wave;
    const float* srow = scores + (size_t)row * S2;
    float vals[32];
#pragma unroll
    for (int i = 0; i < 32; ++i) vals[i] = srow[lane + (i << 6)];

    float topv[16]; int topi[16];
    bool amb = false;
    int nr = 9;
    for (int r = 0; r < 16; ++r) {
        if (r >= nr) break;
        float bvv = -3.4e38f; int bii = 0x7fffffff;
#pragma unroll
        for (int i = 0; i < 32; ++i)
            if (vals[i] > bvv) { bvv = vals[i]; bii = lane + (i << 6); }
#pragma unroll
        for (int off = 32; off > 0; off >>= 1) {
            float ov = __shfl_xor(bvv, off);
            int   oi = __shfl_xor(bii, off);
            if (ov > bvv || (ov == bvv && oi < bii)) { bvv = ov; bii = oi; }
        }
        topv[r] = bvv; topi[r] = bii;
        if ((bii & 63) == lane) vals[bii >> 6] = -3.4e38f;
        if (r == 8) {
            amb = (topv[7] - topv[8]) < TAU;
            if (amb) nr = 16;
        }
    }

    float m = topv[0], w[KTOP], sum = 0.f;
#pragma unroll
    for (int r = 0; r < KTOP; ++r) { w[r] = expf(topv[r] - m); sum += w[r]; }
    float inv = 1.f / sum;
#pragma unroll
    for (int r = 0; r < KTOP; ++r) w[r] *= inv;

    if (amb) {
        int idx = 0;
        if (lane == 0) idx = atomicAdd(ambc, 1);
        idx = __shfl(idx, 0);
        if (idx < AMB_CAP) {
            if (lane == 0) ambgrow[idx] = gbase + row;
            if (lane < 16) cand[idx * 16 + lane] = topi[lane];
            if (lane < KTOP) oldw[idx * KTOP + lane] = w[lane];
            f16* vs = vsave + (size_t)idx * 16 * 768;
            for (int cc = lane; cc < 16 * 96; cc += 64) {
                int cr = cc / 96, ch = cc - cr * 96;
                *(f16x8*)&vs[(size_t)cr * 768 + ch * 8] =
                    *(const f16x8*)&v16r[(size_t)topi[cr] * 768 + ch * 8];
            }
        }
    }

    for (int c = lane; c < 96; c += 64) {
        float o[8] = {0, 0, 0, 0, 0, 0, 0, 0};
#pragma unroll
        for (int r = 0; r < KTOP; ++r) {
            f16x8 vv = *(const f16x8*)&v16r[(size_t)topi[r] * 768 + c * 8];
#pragma unroll
            for (int j = 0; j < 8; ++j) o[j] += w[r] * (float)vv[j];
        }
        f16x8 hx;
#pragma unroll
        for (int j = 0; j < 8; ++j) hx[j] = (f16)o[j];
        size_t fo = ((size_t)(row >> 4) * 24 + (c >> 2)) * 512 +
                    (((row & 15) + ((c & 3) << 4)) << 3);
        *(f16x8*)&retrW[fo] = hx;
    }
}

// ---------------------------------------------------------------------------
// megaScoresProj: [scores tiles (frag, no-LDS) | proj tiles (frag, no-LDS)]
// ---------------------------------------------------------------------------
__global__ __launch_bounds__(256) void megaScoresProj(
    int nSc, const f16* __restrict__ qh, const f16* __restrict__ qm,
    const f16* __restrict__ kh, const f16* __restrict__ km,
    float* __restrict__ scores, float alpha,
    const f16* __restrict__ retrR, const f16* __restrict__ WPh,
    const float* __restrict__ bp, float* __restrict__ outp)
{
    int t = blockIdx.x;
    if (t < nSc) {
        tile_scores_frag(qh, qm, (t >> 4) * 128, kh, km, (t & 15) * 128,
                         scores, alpha);
        return;
    }
    t -= nSc;
    tile_proj_frag(retrR, (t / 6) * 128, WPh, (t % 6) * 128, bp,
                   outp, (t / 6) * 128);
}

// ---------------------------------------------------------------------------
// Deferred exact fixups (post-loop, applied to out). Validated r10/r12/r15.
// ---------------------------------------------------------------------------
__global__ __launch_bounds__(256) void fixA(
    const int* __restrict__ amb_count, const int* __restrict__ amb_grow,
    const float* __restrict__ x, const float* __restrict__ Wq,
    const float* __restrict__ bq, double* __restrict__ q64buf)
{
    int n = *amb_count; if (n > AMB_CAP) n = AMB_CAP;
    const int i = blockIdx.y;
    if (i >= n) return;
    const int tid = threadIdx.x;
    const int jl = tid & 63;
    const int ks = tid >> 6;
    const int j = blockIdx.x * 64 + jl;
    const int grow = amb_grow[i];

    __shared__ float xs[768];
    __shared__ double ps[4][64];
    for (int t = tid; t < 768; t += 256) xs[t] = x[(size_t)grow * 768 + t];
    __syncthreads();

    double a0 = 0.0, a1 = 0.0;
    const float* wp = Wq + j;
    const int k0 = ks * 192;
#pragma unroll 8
    for (int k = 0; k < 192; k += 2) {
        a0 = fma((double)xs[k0 + k],     (double)wp[(size_t)(k0 + k) * 768],     a0);
        a1 = fma((double)xs[k0 + k + 1], (double)wp[(size_t)(k0 + k + 1) * 768], a1);
    }
    ps[ks][jl] = a0 + a1;
    __syncthreads();
    if (ks == 0)
        q64buf[(size_t)i * 768 + j] =
            ((ps[0][jl] + ps[1][jl]) + (ps[2][jl] + ps[3][jl])) + (double)bq[j];
}

__global__ __launch_bounds__(256) void fixB(
    const int* __restrict__ amb_count,
    const float* __restrict__ WkT, const float* __restrict__ bk,
    const double* __restrict__ q64buf,
    double* __restrict__ ubuf, double* __restrict__ bkqbuf)
{
    int n = *amb_count; if (n > AMB_CAP) n = AMB_CAP;
    const int i = blockIdx.y;
    if (i >= n) return;
    const int tid = threadIdx.x;
    const int tl = tid & 63;
    const int js = tid >> 6;
    const int t = blockIdx.x * 64 + tl;

    __shared__ double qs[768];
    __shared__ double ps[4][64];
    const double* qrow = q64buf + (size_t)i * 768;
    for (int k = tid; k < 768; k += 256) qs[k] = qrow[k];
    __syncthreads();

    double a0 = 0.0, a1 = 0.0;
    const float* wp = WkT + t;
    const int j0 = js * 192;
#pragma unroll 8
    for (int k = 0; k < 192; k += 2) {
        a0 = fma((double)wp[(size_t)(j0 + k) * 768],     qs[j0 + k],     a0);
        a1 = fma((double)wp[(size_t)(j0 + k + 1) * 768], qs[j0 + k + 1], a1);
    }
    ps[js][tl] = a0 + a1;
    __syncthreads();
    if (js == 0)
        ubuf[(size_t)i * 768 + t] = (ps[0][tl] + ps[1][tl]) + (ps[2][tl] + ps[3][tl]);

    if (blockIdx.x == 0 && tid < 64) {
        double p = 0.0;
#pragma unroll
        for (int c = 0; c < 12; ++c) {
            int jj = tid + (c << 6);
            p = fma((double)bk[jj], qs[jj], p);
        }
#pragma unroll
        for (int off = 32; off; off >>= 1) p += __shfl_xor(p, off);
        if (tid == 0) bkqbuf[i] = p;
    }
}

__global__ __launch_bounds__(256) void fixC(
    const int* __restrict__ amb_count, const int* __restrict__ amb_grow,
    const float* __restrict__ x, const float* __restrict__ pm,
    const int* __restrict__ cand, const float* __restrict__ oldw,
    const double* __restrict__ ubuf, const double* __restrict__ bkqbuf,
    const f16* __restrict__ vsave, float* __restrict__ dret)
{
    int n = *amb_count; if (n > AMB_CAP) n = AMB_CAP;
    const int i = blockIdx.x;
    if (i >= n) return;
    const int tid = threadIdx.x;
    const int lane = tid & 63;
    const int wave = tid >> 6;
    const int grow = amb_grow[i];
    const float* xb = x + (size_t)(grow >> 12) * TT * 768;

    __shared__ double us[768];
    __shared__ double cs_s[16];
    __shared__ float coef[16];

    const double* urow = ubuf + (size_t)i * 768;
    for (int t = tid; t < 768; t += 256) us[t] = urow[t];
    __syncthreads();

    const double ISQ = 1.0 / sqrt((double)DD);
    const double bkq = bkqbuf[i];
#pragma unroll
    for (int c = wave; c < 16; c += 4) {
        int s = cand[i * 16 + c];
        double p = 0.0;
        if (s < SS) {
            const float* xr = xb + (size_t)(4 * s) * 768;
#pragma unroll
            for (int t = 0; t < 12; ++t) {
                int j2 = lane + (t << 6);
                double sv = 0.25 * ((double)xr[j2] + (double)xr[j2 + 768] +
                                    (double)xr[j2 + 1536] + (double)xr[j2 + 2304]);
                p = fma(sv, us[j2], p);
            }
        } else {
            const float* pr = pm + (size_t)(s - SS) * 768;
#pragma unroll
            for (int t = 0; t < 12; ++t) {
                int j2 = lane + (t << 6);
                p = fma((double)pr[j2], us[j2], p);
            }
        }
#pragma unroll
        for (int off = 32; off; off >>= 1) p += __shfl_xor(p, off);
        if (lane == 0) cs_s[c] = (p + bkq) * ISQ;
    }
    __syncthreads();

    if (tid == 0) {
        double cs[16]; int ci[16];
        for (int c = 0; c < 16; ++c) { cs[c] = cs_s[c]; ci[c] = cand[i * 16 + c]; }
        unsigned used = 0;
        double sv[KTOP]; int sp[KTOP];
        for (int r = 0; r < KTOP; ++r) {
            int bi = -1;
            for (int c = 0; c < 16; ++c) {
                if (used & (1u << c)) continue;
                if (bi < 0 || cs[c] > cs[bi] ||
                    (cs[c] == cs[bi] && ci[c] < ci[bi])) bi = c;
            }
            used |= (1u << bi); sv[r] = cs[bi]; sp[r] = bi;
        }
        double mx = sv[0], es[KTOP], ssum = 0.0;
        for (int r = 0; r < KTOP; ++r) { es[r] = exp(sv[r] - mx); ssum += es[r]; }
        for (int c = 0; c < 16; ++c) coef[c] = (c < KTOP) ? -oldw[i * KTOP + c] : 0.f;
        for (int r = 0; r < KTOP; ++r) coef[sp[r]] += (float)(es[r] / ssum);
    }
    __syncthreads();

    const f16* vs = vsave + (size_t)i * 16 * 768;
    for (int j = tid; j < 768; j += 256) {
        float d = 0.f;
#pragma unroll
        for (int c = 0; c < 16; ++c) d += coef[c] * (float)vs[(size_t)c * 768 + j];
        dret[(size_t)i * 768 + j] = d;
    }
}

__global__ __launch_bounds__(256) void fixD(
    const int* __restrict__ amb_count, const int* __restrict__ amb_grow,
    const float* __restrict__ dret, const float* __restrict__ Wp,
    float* __restrict__ out)
{
    int n = *amb_count; if (n > AMB_CAP) n = AMB_CAP;
    const int i = blockIdx.y;
    if (i >= n) return;
    const int tid = threadIdx.x;
    const int jl = tid & 63;
    const int ks = tid >> 6;
    const int j = blockIdx.x * 64 + jl;
    const int grow = amb_grow[i];

    __shared__ float ds[768];
    __shared__ float ps[4][64];
    for (int t = tid; t < 768; t += 256) ds[t] = dret[(size_t)i * 768 + t];
    __syncthreads();

    float a0 = 0.f, a1 = 0.f;
    const float* wp = Wp + j;
    const int k0 = ks * 192;
#pragma unroll 8
    for (int k = 0; k < 192; k += 2) {
        a0 = fmaf(ds[k0 + k],     wp[(size_t)(k0 + k) * 768],     a0);
        a1 = fmaf(ds[k0 + k + 1], wp[(size_t)(k0 + k + 1) * 768], a1);
    }
    ps[ks][jl] = a0 + a1;
    __syncthreads();
    if (ks == 0)
        out[(size_t)grow * 768 + j] +=
            RWEIGHT * ((ps[0][jl] + ps[1][jl]) + (ps[2][jl] + ps[3][jl]));
}

// ---------------------------------------------------------------------------
extern "C" void kernel_launch(void* const* d_in, const int* in_sizes, int n_in,
                              void* d_out, int out_size, void* d_ws, size_t ws_size,
                              hipStream_t stream)
{
    const float* x  = (const float*)d_in[0];
    const float* Wq = (const float*)d_in[1];
    const float* bq = (const float*)d_in[2];
    const float* Wk = (const float*)d_in[3];
    const float* bk = (const float*)d_in[4];
    const float* Wv = (const float*)d_in[5];
    const float* bv = (const float*)d_in[6];
    const float* Wp = (const float*)d_in[7];
    const float* bp = (const float*)d_in[8];
    const float* pm = (const float*)d_in[9];
    float* out = (float*)d_out;
    float* ws  = (float*)d_ws;

    const float inv_sqrt_d = (float)(1.0 / sqrt((double)DD));
    const size_t TD  = (size_t)TT * DD;
    const size_t SD  = (size_t)SS * DD;
    const size_t WSZ = (size_t)DD * DD;

    float* p = ws;
    f16* WQh = (f16*)p; p += WSZ / 2;
    f16* WQm = (f16*)p; p += WSZ / 2;
    f16* WKh = (f16*)p; p += WSZ / 2;
    f16* WKm = (f16*)p; p += WSZ / 2;
    f16* WVh = (f16*)p; p += WSZ / 2;
    f16* WPh = (f16*)p; p += WSZ / 2;
    float* WkT32 = p; p += WSZ;
    float* slots_all = p; p += (size_t)BB * SD;
    f16* qh = (f16*)p; p += TD / 2;
    f16* qm = (f16*)p; p += TD / 2;
    f16* kh = (f16*)p; p += SD;             // [2S][768] f16 (frag)
    f16* km = (f16*)p; p += SD;
    f16* v16a = (f16*)p; p += SD;
    f16* v16b = (f16*)p; p += SD;
    f16* retrA = (f16*)p; p += TD / 2;
    f16* retrB = (f16*)p; p += TD / 2;
    double* q64buf = (double*)p; p += (size_t)AMB_CAP * DD * 2;
    double* ubuf   = (double*)p; p += (size_t)AMB_CAP * DD * 2;
    double* bkqbuf = (double*)p; p += AMB_CAP * 2;
    int* cand = (int*)p; p += (size_t)AMB_CAP * 16;
    float* oldw = p; p += (size_t)AMB_CAP * KTOP;
    f16* vsave = (f16*)p; p += (size_t)AMB_CAP * 16 * DD / 2;
    float* dret = p; p += (size_t)AMB_CAP * DD;
    int* ambc = (int*)p; p += 64;
    int* ambgrow = (int*)p; p += AMB_CAP;
    float* scores = p;                      // [4096][2048]

    transpose_split<<<dim3(24, 24, 4), 256, 0, stream>>>(
        Wq, Wk, Wv, Wp, WQh, WQm, WKh, WKm, WVh, WPh, WkT32);
    zeroN<<<1, 64, 0, stream>>>(ambc);
    build_pooled_all<<<(BB * SS * DD) / 256, 256, 0, stream>>>(x, slots_all);

    // L0: producers for batch 0 + pm halves (k once; v pm into both bufs).
    megaSelProd<<<432, 256, 0, stream>>>(
        0, nullptr, nullptr, nullptr, 0, ambc, ambgrow, cand, oldw, vsave,
        1, 1, 1, x, slots_all, pm,
        WQh, WQm, WKh, WKm, WVh, bq, bk, bv, qh, qm, kh, km, v16a, v16b);
    // M0: scores(0).
    megaScoresProj<<<512, 256, 0, stream>>>(
        512, qh, qm, kh, km, scores, inv_sqrt_d, nullptr, WPh, bp, nullptr);

    for (int b = 1; b < BB; ++b) {
        f16* v16w = (b & 1) ? v16b : v16a;       // P(b) writes
        f16* v16r = ((b - 1) & 1) ? v16b : v16a; // C(b-1) reads
        f16* retrW = ((b - 1) & 1) ? retrB : retrA;

        // L(b): producers(b) tiles | select(b-1)
        megaSelProd<<<1312, 256, 0, stream>>>(
            1024, scores, v16r, retrW, (b - 1) * TT,
            ambc, ambgrow, cand, oldw, vsave,
            1, 1, 0, x + (size_t)b * TD, slots_all + (size_t)b * SD, nullptr,
            WQh, WQm, WKh, WKm, WVh, bq, bk, bv, qh, qm, kh, km, v16w, nullptr);
        // M(b): scores(b) | proj(b-1)
        megaScoresProj<<<704, 256, 0, stream>>>(
            512, qh, qm, kh, km, scores, inv_sqrt_d,
            retrW, WPh, bp, out + (size_t)(b - 1) * TD);
    }

    // L4: select(3) only.
    f16* v16r3 = v16b;           // (3&1) -> v16b
    f16* retrW3 = retrB;
    megaSelProd<<<1024, 256, 0, stream>>>(
        1024, scores, v16r3, retrW3, 3 * TT,
        ambc, ambgrow, cand, oldw, vsave,
        0, 0, 0, nullptr, nullptr, nullptr,
        WQh, WQm, WKh, WKm, WVh, bq, bk, bv, qh, qm, kh, km, nullptr, nullptr);
    // M4: proj(3) only.
    megaScoresProj<<<192, 256, 0, stream>>>(
        0, nullptr, nullptr, nullptr, nullptr, nullptr, 0.f,
        retrW3, WPh, bp, out + (size_t)3 * TD);

    // deferred exact fixups.
    fixA<<<dim3(12, AMB_CAP), 256, 0, stream>>>(ambc, ambgrow, x, Wq, bq, q64buf);
    fixB<<<dim3(12, AMB_CAP), 256, 0, stream>>>(ambc, WkT32, bk, q64buf, ubuf, bkqbuf);
    fixC<<<AMB_CAP, 256, 0, stream>>>(ambc, ambgrow, x, pm, cand, oldw,
                                      ubuf, bkqbuf, vsave, dret);
    fixD<<<dim3(12, AMB_CAP), 256, 0, stream>>>(ambc, ambgrow, dret, Wp, out);
}

// Round 19
// 621.052 us; speedup vs baseline: 1.0689x; 1.0689x over previous
//
#include <hip/hip_runtime.h>
#include <math.h>

#define BB 4
#define TT 4096
#define DD 768
#define SS 1024
#define S2 2048
#define KTOP 8
#define RWEIGHT 0.1f
#define TAU 2e-4f
#define AMB_CAP 256

typedef __attribute__((ext_vector_type(8))) _Float16 f16x8;
typedef __attribute__((ext_vector_type(4))) float f32x4;
typedef _Float16 f16;

// Fragment-plane addressing (weights only):
// lane l's f16x8 fragment for block (rb,kb) at ((rb*24+kb)*512 + l*8).
__device__ __forceinline__ size_t fragoff(int row, int k) {
    return ((size_t)(row >> 4) * 24 + (k >> 5)) * 512 +
           (((row & 15) + (((k >> 3) & 3) << 4)) << 3) + (k & 7);
}

// ---------------------------------------------------------------------------
__global__ __launch_bounds__(256) void build_pooled_all(
    const float* __restrict__ x, float* __restrict__ slots)
{
    int i = blockIdx.x * 256 + threadIdx.x;     // over B*S*D = 3145728
    int s2 = i / DD;
    int d = i - s2 * DD;
    int b = s2 >> 10, s = s2 & 1023;
    const float* xb = x + (size_t)b * TT * DD + (size_t)(4 * s) * DD + d;
    slots[i] = 0.25f * (xb[0] + xb[DD] + xb[2 * DD] + xb[3 * DD]);
}

// ---------------------------------------------------------------------------
// transpose_split: weight planes in FRAGMENT layout + f32 WkT (fixB).
// ---------------------------------------------------------------------------
__global__ __launch_bounds__(256) void transpose_split(
    const float* __restrict__ W0, const float* __restrict__ W1,
    const float* __restrict__ W2, const float* __restrict__ W3,
    f16* __restrict__ WQh, f16* __restrict__ WQm,
    f16* __restrict__ WKh, f16* __restrict__ WKm,
    f16* __restrict__ WVh, f16* __restrict__ WPh,
    float* __restrict__ WkT32)
{
    const int z = blockIdx.z;
    const float* W = (z == 0) ? W0 : (z == 1) ? W1 : (z == 2) ? W2 : W3;
    __shared__ float t[32][33];
    int bx = blockIdx.x * 32, by = blockIdx.y * 32;
    int lx = threadIdx.x & 31, ly = threadIdx.x >> 5;
#pragma unroll
    for (int r = 0; r < 32; r += 8)
        t[ly + r][lx] = W[(size_t)(bx + ly + r) * 768 + by + lx];
    __syncthreads();
#pragma unroll
    for (int r = 0; r < 32; r += 8) {
        float w = t[lx][ly + r];
        int n = by + ly + r, k = bx + lx;        // W^T[n][k]
        size_t fo = fragoff(n, k);
        f16 h = (f16)w;
        if (z == 0) { WQh[fo] = h; WQm[fo] = (f16)(w - (float)h); }
        else if (z == 1) { WKh[fo] = h; WKm[fo] = (f16)(w - (float)h);
                           WkT32[(size_t)n * 768 + k] = w; }
        else if (z == 2) { WVh[fo] = h; }
        else { WPh[fo] = h; }
    }
}

__global__ void zeroN(int* p) { p[threadIdx.x] = 0; }

// ---------------------------------------------------------------------------
// A-staging swizzle (verified r8): p(c,r)=c^(r&3)^((r>>2)&1);
// csw = ((l>>4)^(l&3)^((l>>2)&1))*8.
// ---------------------------------------------------------------------------
// 3-pass split producer (q,k): A f32 staged+split (reg-prefetch pipeline),
// B frag-direct, output h/m planes ROW-major.
__device__ __forceinline__ void tile_split_prod(
    const float* __restrict__ A, int arow0,
    const f16* __restrict__ BhF, const f16* __restrict__ BmF, int bncol,
    const float* __restrict__ bias,
    f16* __restrict__ Ch, f16* __restrict__ Cm, int crow0,
    f16* LAh, f16* LAm)
{
    const int tid = threadIdx.x;
    const int lane = tid & 63;
    const int wc = (tid >> 6) & 1;
    const int wr = (tid >> 7) & 1;
    const int srow = tid >> 1, c0 = tid & 1;
    const int p0 = c0 ^ (srow & 3) ^ ((srow >> 2) & 1);
    const int wo0 = srow * 32 + p0 * 8, wo1 = wo0 ^ 16;
    const int csw = (((lane >> 4) ^ (lane & 3) ^ ((lane >> 2) & 1)) * 8);

    f32x4 acc[4][4];
#pragma unroll
    for (int i = 0; i < 4; ++i)
#pragma unroll
        for (int j = 0; j < 4; ++j) acc[i][j] = (f32x4){0.f, 0.f, 0.f, 0.f};

    const float* pa = A + (size_t)(arow0 + srow) * 768 + c0 * 8;
    const int rbB0 = bncol / 16 + wc * 4;

    float4 a0 = *(const float4*)(pa);
    float4 a1 = *(const float4*)(pa + 4);
    float4 a2 = *(const float4*)(pa + 16);
    float4 a3 = *(const float4*)(pa + 20);

    for (int kb = 0; kb < 24; ++kb) {
        __syncthreads();
        {
            float av[16] = {a0.x, a0.y, a0.z, a0.w, a1.x, a1.y, a1.z, a1.w,
                            a2.x, a2.y, a2.z, a2.w, a3.x, a3.y, a3.z, a3.w};
            f16x8 h, m;
#pragma unroll
            for (int j = 0; j < 8; ++j) {
                f16 hh = (f16)av[j]; h[j] = hh; m[j] = (f16)(av[j] - (float)hh);
            }
            *(f16x8*)&LAh[wo0] = h; *(f16x8*)&LAm[wo0] = m;
#pragma unroll
            for (int j = 0; j < 8; ++j) {
                f16 hh = (f16)av[j + 8]; h[j] = hh; m[j] = (f16)(av[j + 8] - (float)hh);
            }
            *(f16x8*)&LAh[wo1] = h; *(f16x8*)&LAm[wo1] = m;
        }
        __syncthreads();

        if (kb + 1 < 24) {                    // prefetch next A k-step
            int k0 = (kb + 1) * 32;
            a0 = *(const float4*)(pa + k0);
            a1 = *(const float4*)(pa + k0 + 4);
            a2 = *(const float4*)(pa + k0 + 16);
            a3 = *(const float4*)(pa + k0 + 20);
        }

        f16x8 fbh[4], fbm[4];
#pragma unroll
        for (int ni = 0; ni < 4; ++ni) {
            size_t off = ((size_t)(rbB0 + ni) * 24 + kb) * 512 + lane * 8;
            fbh[ni] = *(const f16x8*)&BhF[off];
            fbm[ni] = *(const f16x8*)&BmF[off];
        }
        f16x8 fah[4], fam[4];
#pragma unroll
        for (int mi = 0; mi < 4; ++mi) {
            int off = (wr * 64 + mi * 16 + (lane & 15)) * 32 + csw;
            fah[mi] = *(const f16x8*)&LAh[off];
            fam[mi] = *(const f16x8*)&LAm[off];
        }
#pragma unroll
        for (int mi = 0; mi < 4; ++mi)
#pragma unroll
            for (int ni = 0; ni < 4; ++ni) {
                acc[mi][ni] = __builtin_amdgcn_mfma_f32_16x16x32_f16(
                    fah[mi], fbh[ni], acc[mi][ni], 0, 0, 0);
                acc[mi][ni] = __builtin_amdgcn_mfma_f32_16x16x32_f16(
                    fah[mi], fbm[ni], acc[mi][ni], 0, 0, 0);
                acc[mi][ni] = __builtin_amdgcn_mfma_f32_16x16x32_f16(
                    fam[mi], fbh[ni], acc[mi][ni], 0, 0, 0);
            }
    }

    const int orow0 = wr * 64 + (lane >> 4) * 4;
    const int ocol0 = wc * 64 + (lane & 15);
#pragma unroll
    for (int mi = 0; mi < 4; ++mi)
#pragma unroll
        for (int ni = 0; ni < 4; ++ni) {
            size_t col = (size_t)bncol + ocol0 + ni * 16;
            float badd = bias[col];
            size_t rbase = (size_t)crow0 + orow0 + mi * 16;
#pragma unroll
            for (int r = 0; r < 4; ++r) {
                float val = acc[mi][ni][r] + badd;
                f16 h = (f16)val;
                size_t idx = (rbase + r) * 768 + col;
                Ch[idx] = h;
                Cm[idx] = (f16)(val - (float)h);
            }
        }
}

// 1-pass producer (v): A f32 staged (reg-prefetch), B frag-direct, v16 ROW-major.
__device__ __forceinline__ void tile_1p_prod(
    const float* __restrict__ A, int arow0,
    const f16* __restrict__ BhF, int bncol,
    const float* __restrict__ bias,
    f16* __restrict__ Co, int crow0, f16* LA)
{
    const int tid = threadIdx.x;
    const int lane = tid & 63;
    const int wc = (tid >> 6) & 1;
    const int wr = (tid >> 7) & 1;
    const int srow = tid >> 1, c0 = tid & 1;
    const int p0 = c0 ^ (srow & 3) ^ ((srow >> 2) & 1);
    const int wo0 = srow * 32 + p0 * 8, wo1 = wo0 ^ 16;
    const int csw = (((lane >> 4) ^ (lane & 3) ^ ((lane >> 2) & 1)) * 8);

    f32x4 acc[4][4];
#pragma unroll
    for (int i = 0; i < 4; ++i)
#pragma unroll
        for (int j = 0; j < 4; ++j) acc[i][j] = (f32x4){0.f, 0.f, 0.f, 0.f};

    const float* pa = A + (size_t)(arow0 + srow) * 768 + c0 * 8;
    const int rbB0 = bncol / 16 + wc * 4;

    float4 a0 = *(const float4*)(pa);
    float4 a1 = *(const float4*)(pa + 4);
    float4 a2 = *(const float4*)(pa + 16);
    float4 a3 = *(const float4*)(pa + 20);

    for (int kb = 0; kb < 24; ++kb) {
        __syncthreads();
        {
            f16x8 h;
            h[0] = (f16)a0.x; h[1] = (f16)a0.y; h[2] = (f16)a0.z; h[3] = (f16)a0.w;
            h[4] = (f16)a1.x; h[5] = (f16)a1.y; h[6] = (f16)a1.z; h[7] = (f16)a1.w;
            *(f16x8*)&LA[wo0] = h;
            h[0] = (f16)a2.x; h[1] = (f16)a2.y; h[2] = (f16)a2.z; h[3] = (f16)a2.w;
            h[4] = (f16)a3.x; h[5] = (f16)a3.y; h[6] = (f16)a3.z; h[7] = (f16)a3.w;
            *(f16x8*)&LA[wo1] = h;
        }
        __syncthreads();

        if (kb + 1 < 24) {
            int k0 = (kb + 1) * 32;
            a0 = *(const float4*)(pa + k0);
            a1 = *(const float4*)(pa + k0 + 4);
            a2 = *(const float4*)(pa + k0 + 16);
            a3 = *(const float4*)(pa + k0 + 20);
        }

        f16x8 fbh[4];
#pragma unroll
        for (int ni = 0; ni < 4; ++ni)
            fbh[ni] = *(const f16x8*)&BhF[((size_t)(rbB0 + ni) * 24 + kb) * 512 + lane * 8];
        f16x8 fah[4];
#pragma unroll
        for (int mi = 0; mi < 4; ++mi)
            fah[mi] = *(const f16x8*)&LA[(wr * 64 + mi * 16 + (lane & 15)) * 32 + csw];
#pragma unroll
        for (int mi = 0; mi < 4; ++mi)
#pragma unroll
            for (int ni = 0; ni < 4; ++ni)
                acc[mi][ni] = __builtin_amdgcn_mfma_f32_16x16x32_f16(
                    fah[mi], fbh[ni], acc[mi][ni], 0, 0, 0);
    }

    const int orow0 = wr * 64 + (lane >> 4) * 4;
    const int ocol0 = wc * 64 + (lane & 15);
#pragma unroll
    for (int mi = 0; mi < 4; ++mi)
#pragma unroll
        for (int ni = 0; ni < 4; ++ni) {
            size_t col = (size_t)bncol + ocol0 + ni * 16;
            float badd = bias[col];
            size_t rbase = (size_t)crow0 + orow0 + mi * 16;
#pragma unroll
            for (int r = 0; r < 4; ++r)
                Co[(rbase + r) * 768 + col] = (f16)(acc[mi][ni][r] + badd);
        }
}

// proj: A (retr f16 row-major) staged w/ prefetch; B (WPh) frag-direct.
__device__ __forceinline__ void tile_proj(
    const f16* __restrict__ A, int arow0,
    const f16* __restrict__ BhF, int bncol,
    const float* __restrict__ bias,
    float* __restrict__ Co, int crow0, f16* LA)
{
    const int tid = threadIdx.x;
    const int lane = tid & 63;
    const int wc = (tid >> 6) & 1;
    const int wr = (tid >> 7) & 1;
    const int srow = tid >> 1, c0 = tid & 1;
    const int p0 = c0 ^ (srow & 3) ^ ((srow >> 2) & 1);
    const int wo0 = srow * 32 + p0 * 8, wo1 = wo0 ^ 16;
    const int csw = (((lane >> 4) ^ (lane & 3) ^ ((lane >> 2) & 1)) * 8);

    f32x4 acc[4][4];
#pragma unroll
    for (int i = 0; i < 4; ++i)
#pragma unroll
        for (int j = 0; j < 4; ++j) acc[i][j] = (f32x4){0.f, 0.f, 0.f, 0.f};

    const f16* pa = A + (size_t)(arow0 + srow) * 768 + c0 * 8;
    const int rbB0 = bncol / 16 + wc * 4;

    f16x8 ah0 = *(const f16x8*)(pa);
    f16x8 ah1 = *(const f16x8*)(pa + 16);

    for (int kb = 0; kb < 24; ++kb) {
        __syncthreads();
        *(f16x8*)&LA[wo0] = ah0;
        *(f16x8*)&LA[wo1] = ah1;
        __syncthreads();

        if (kb + 1 < 24) {
            int k0 = (kb + 1) * 32;
            ah0 = *(const f16x8*)(pa + k0);
            ah1 = *(const f16x8*)(pa + k0 + 16);
        }

        f16x8 fbh[4];
#pragma unroll
        for (int ni = 0; ni < 4; ++ni)
            fbh[ni] = *(const f16x8*)&BhF[((size_t)(rbB0 + ni) * 24 + kb) * 512 + lane * 8];
        f16x8 fah[4];
#pragma unroll
        for (int mi = 0; mi < 4; ++mi)
            fah[mi] = *(const f16x8*)&LA[(wr * 64 + mi * 16 + (lane & 15)) * 32 + csw];
#pragma unroll
        for (int mi = 0; mi < 4; ++mi)
#pragma unroll
            for (int ni = 0; ni < 4; ++ni)
                acc[mi][ni] = __builtin_amdgcn_mfma_f32_16x16x32_f16(
                    fah[mi], fbh[ni], acc[mi][ni], 0, 0, 0);
    }

    const int orow0 = wr * 64 + (lane >> 4) * 4;
    const int ocol0 = wc * 64 + (lane & 15);
#pragma unroll
    for (int mi = 0; mi < 4; ++mi)
#pragma unroll
        for (int ni = 0; ni < 4; ++ni) {
            size_t col = (size_t)bncol + ocol0 + ni * 16;
            float badd = RWEIGHT * bias[col];
            size_t rbase = (size_t)crow0 + orow0 + mi * 16;
#pragma unroll
            for (int r = 0; r < 4; ++r)
                Co[(rbase + r) * 768 + col] = RWEIGHT * acc[mi][ni][r] + badd;
        }
}

// 3-pass scores from ROW-major h/m planes (LDS, reg-prefetch). Validated r17.
__device__ __forceinline__ void tile_scores_planes(
    const f16* __restrict__ qh, const f16* __restrict__ qm, int arow0,
    const f16* __restrict__ kh, const f16* __restrict__ km, int bncol,
    float* __restrict__ C, float alpha,
    f16* LAh, f16* LAm, f16* LBh, f16* LBm)
{
    const int tid = threadIdx.x;
    const int lane = tid & 63;
    const int wc = (tid >> 6) & 1;
    const int wr = (tid >> 7) & 1;
    const int srow = tid >> 1, c0 = tid & 1;
    const int p0 = c0 ^ (srow & 3) ^ ((srow >> 2) & 1);
    const int wo0 = srow * 32 + p0 * 8, wo1 = wo0 ^ 16;
    const int csw = (((lane >> 4) ^ (lane & 3) ^ ((lane >> 2) & 1)) * 8);
    const size_t bn = (size_t)bncol;

    f32x4 acc[4][4];
#pragma unroll
    for (int i = 0; i < 4; ++i)
#pragma unroll
        for (int j = 0; j < 4; ++j) acc[i][j] = (f32x4){0.f, 0.f, 0.f, 0.f};

    const f16* pah = qh + (size_t)(arow0 + srow) * 768 + c0 * 8;
    const f16* pam = qm + (size_t)(arow0 + srow) * 768 + c0 * 8;
    const f16* pbh = kh + (bn + srow) * 768 + c0 * 8;
    const f16* pbm = km + (bn + srow) * 768 + c0 * 8;

    f16x8 ah0 = *(const f16x8*)(pah);
    f16x8 ah1 = *(const f16x8*)(pah + 16);
    f16x8 am0 = *(const f16x8*)(pam);
    f16x8 am1 = *(const f16x8*)(pam + 16);
    f16x8 bh0 = *(const f16x8*)(pbh);
    f16x8 bh1 = *(const f16x8*)(pbh + 16);
    f16x8 bm0 = *(const f16x8*)(pbm);
    f16x8 bm1 = *(const f16x8*)(pbm + 16);

    for (int k0 = 0; k0 < 768; k0 += 32) {
        __syncthreads();
        *(f16x8*)&LAh[wo0] = ah0; *(f16x8*)&LAh[wo1] = ah1;
        *(f16x8*)&LAm[wo0] = am0; *(f16x8*)&LAm[wo1] = am1;
        *(f16x8*)&LBh[wo0] = bh0; *(f16x8*)&LBh[wo1] = bh1;
        *(f16x8*)&LBm[wo0] = bm0; *(f16x8*)&LBm[wo1] = bm1;
        __syncthreads();

        if (k0 + 32 < 768) {
            ah0 = *(const f16x8*)(pah + k0 + 32);
            ah1 = *(const f16x8*)(pah + k0 + 48);
            am0 = *(const f16x8*)(pam + k0 + 32);
            am1 = *(const f16x8*)(pam + k0 + 48);
            bh0 = *(const f16x8*)(pbh + k0 + 32);
            bh1 = *(const f16x8*)(pbh + k0 + 48);
            bm0 = *(const f16x8*)(pbm + k0 + 32);
            bm1 = *(const f16x8*)(pbm + k0 + 48);
        }

        f16x8 fah[4], fam[4], fbh[4], fbm[4];
#pragma unroll
        for (int mi = 0; mi < 4; ++mi) {
            int off = (wr * 64 + mi * 16 + (lane & 15)) * 32 + csw;
            fah[mi] = *(const f16x8*)&LAh[off];
            fam[mi] = *(const f16x8*)&LAm[off];
        }
#pragma unroll
        for (int ni = 0; ni < 4; ++ni) {
            int off = (wc * 64 + ni * 16 + (lane & 15)) * 32 + csw;
            fbh[ni] = *(const f16x8*)&LBh[off];
            fbm[ni] = *(const f16x8*)&LBm[off];
        }
#pragma unroll
        for (int mi = 0; mi < 4; ++mi)
#pragma unroll
            for (int ni = 0; ni < 4; ++ni) {
                acc[mi][ni] = __builtin_amdgcn_mfma_f32_16x16x32_f16(
                    fah[mi], fbh[ni], acc[mi][ni], 0, 0, 0);
                acc[mi][ni] = __builtin_amdgcn_mfma_f32_16x16x32_f16(
                    fah[mi], fbm[ni], acc[mi][ni], 0, 0, 0);
                acc[mi][ni] = __builtin_amdgcn_mfma_f32_16x16x32_f16(
                    fam[mi], fbh[ni], acc[mi][ni], 0, 0, 0);
            }
    }

    const int orow0 = wr * 64 + (lane >> 4) * 4;
    const int ocol0 = wc * 64 + (lane & 15);
#pragma unroll
    for (int mi = 0; mi < 4; ++mi)
#pragma unroll
        for (int ni = 0; ni < 4; ++ni) {
            size_t col = bn + ocol0 + ni * 16;
            size_t rbase = (size_t)arow0 + orow0 + mi * 16;
#pragma unroll
            for (int r = 0; r < 4; ++r)
                C[(rbase + r) * S2 + col] = alpha * acc[mi][ni][r];
        }
}

// ---------------------------------------------------------------------------
// megaSelProd: [q tiles | k tiles | v tiles | select rows of prev batch]
// LDS 16 KB.
// ---------------------------------------------------------------------------
__global__ __launch_bounds__(256) void megaSelProd(
    int nSel, const float* __restrict__ scores, const f16* __restrict__ v16r,
    f16* __restrict__ retrW, int gbase,
    int* __restrict__ ambc, int* __restrict__ ambgrow, int* __restrict__ cand,
    float* __restrict__ oldw, f16* __restrict__ vsave,
    int hasQ, int hasKV, int doPm,
    const float* __restrict__ xq, const float* __restrict__ slots_b,
    const float* __restrict__ pm,
    const f16* __restrict__ WQh, const f16* __restrict__ WQm,
    const f16* __restrict__ WKh, const f16* __restrict__ WKm,
    const f16* __restrict__ WVh,
    const float* __restrict__ bq, const float* __restrict__ bk,
    const float* __restrict__ bv,
    f16* __restrict__ qh, f16* __restrict__ qm,
    f16* __restrict__ kh, f16* __restrict__ km,
    f16* __restrict__ v16w, f16* __restrict__ v16w2)
{
    __shared__ f16 LAh[4096], LAm[4096];
    int t = blockIdx.x;

    if (hasQ) {
        if (t < 192) {
            tile_split_prod(xq, (t / 6) * 128, WQh, WQm, (t % 6) * 128, bq,
                            qh, qm, (t / 6) * 128, LAh, LAm);
            return;
        }
        t -= 192;
    }
    if (hasKV) {
        if (t < 48) {
            tile_split_prod(slots_b, (t / 6) * 128, WKh, WKm, (t % 6) * 128, bk,
                            kh, km, (t / 6) * 128, LAh, LAm);
            return;
        }
        t -= 48;
        if (doPm) {
            if (t < 48) {
                tile_split_prod(pm, (t / 6) * 128, WKh, WKm, (t % 6) * 128, bk,
                                kh, km, 1024 + (t / 6) * 128, LAh, LAm);
                return;
            }
            t -= 48;
        }
        if (t < 48) {
            tile_1p_prod(slots_b, (t / 6) * 128, WVh, (t % 6) * 128, bv,
                         v16w, (t / 6) * 128, LAh);
            return;
        }
        t -= 48;
        if (doPm) {
            if (t < 48) {
                tile_1p_prod(pm, (t / 6) * 128, WVh, (t % 6) * 128, bv,
                             v16w, 1024 + (t / 6) * 128, LAh);
                return;
            }
            t -= 48;
            if (t < 48) {
                tile_1p_prod(pm, (t / 6) * 128, WVh, (t % 6) * 128, bv,
                             v16w2, 1024 + (t / 6) * 128, LAh);
                return;
            }
            t -= 48;
        }
    }
    if (t >= nSel) return;

    // ----- select_combine: one wave per row; retr ROW-major -----
    const int lane = threadIdx.x & 63;
    const int wave = threadIdx.x >> 6;
    const int row = t * 4 + wave;
    const float* srow = scores + (size_t)row * S2;
    float vals[32];
#pragma unroll
    for (int i = 0; i < 32; ++i) vals[i] = srow[lane + (i << 6)];

    float topv[16]; int topi[16];
    bool amb = false;
    int nr = 9;
    for (int r = 0; r < 16; ++r) {
        if (r >= nr) break;
        float bvv = -3.4e38f; int bii = 0x7fffffff;
#pragma unroll
        for (int i = 0; i < 32; ++i)
            if (vals[i] > bvv) { bvv = vals[i]; bii = lane + (i << 6); }
#pragma unroll
        for (int off = 32; off > 0; off >>= 1) {
            float ov = __shfl_xor(bvv, off);
            int   oi = __shfl_xor(bii, off);
            if (ov > bvv || (ov == bvv && oi < bii)) { bvv = ov; bii = oi; }
        }
        topv[r] = bvv; topi[r] = bii;
        if ((bii & 63) == lane) vals[bii >> 6] = -3.4e38f;
        if (r == 8) {
            amb = (topv[7] - topv[8]) < TAU;
            if (amb) nr = 16;
        }
    }

    float m = topv[0], w[KTOP], sum = 0.f;
#pragma unroll
    for (int r = 0; r < KTOP; ++r) { w[r] = expf(topv[r] - m); sum += w[r]; }
    float inv = 1.f / sum;
#pragma unroll
    for (int r = 0; r < KTOP; ++r) w[r] *= inv;

    if (amb) {
        int idx = 0;
        if (lane == 0) idx = atomicAdd(ambc, 1);
        idx = __shfl(idx, 0);
        if (idx < AMB_CAP) {
            if (lane == 0) ambgrow[idx] = gbase + row;
            if (lane < 16) cand[idx * 16 + lane] = topi[lane];
            if (lane < KTOP) oldw[idx * KTOP + lane] = w[lane];
            f16* vs = vsave + (size_t)idx * 16 * 768;
            for (int cc = lane; cc < 16 * 96; cc += 64) {
                int cr = cc / 96, ch = cc - cr * 96;
                *(f16x8*)&vs[(size_t)cr * 768 + ch * 8] =
                    *(const f16x8*)&v16r[(size_t)topi[cr] * 768 + ch * 8];
            }
        }
    }

    for (int c = lane; c < 96; c += 64) {
        float o[8] = {0, 0, 0, 0, 0, 0, 0, 0};
#pragma unroll
        for (int r = 0; r < KTOP; ++r) {
            f16x8 vv = *(const f16x8*)&v16r[(size_t)topi[r] * 768 + c * 8];
#pragma unroll
            for (int j = 0; j < 8; ++j) o[j] += w[r] * (float)vv[j];
        }
        f16x8 hx;
#pragma unroll
        for (int j = 0; j < 8; ++j) hx[j] = (f16)o[j];
        *(f16x8*)&retrW[(size_t)row * 768 + c * 8] = hx;
    }
}

// ---------------------------------------------------------------------------
// megaScoresProj: [scores tiles (LDS) | proj tiles (A-LDS, B-frag)]
// ---------------------------------------------------------------------------
__global__ __launch_bounds__(256) void megaScoresProj(
    int nSc, const f16* __restrict__ qh, const f16* __restrict__ qm,
    const f16* __restrict__ kh, const f16* __restrict__ km,
    float* __restrict__ scores, float alpha,
    const f16* __restrict__ retrR, const f16* __restrict__ WPh,
    const float* __restrict__ bp, float* __restrict__ outp)
{
    __shared__ f16 LAh[4096], LAm[4096], LBh[4096], LBm[4096];
    int t = blockIdx.x;
    if (t < nSc) {
        tile_scores_planes(qh, qm, (t >> 4) * 128, kh, km, (t & 15) * 128,
                           scores, alpha, LAh, LAm, LBh, LBm);
        return;
    }
    t -= nSc;
    tile_proj(retrR, (t / 6) * 128, WPh, (t % 6) * 128, bp,
              outp, (t / 6) * 128, LAh);
}

// ---------------------------------------------------------------------------
// Deferred exact fixups (post-loop, applied to out). Validated r10/r12/r15.
// ---------------------------------------------------------------------------
__global__ __launch_bounds__(256) void fixA(
    const int* __restrict__ amb_count, const int* __restrict__ amb_grow,
    const float* __restrict__ x, const float* __restrict__ Wq,
    const float* __restrict__ bq, double* __restrict__ q64buf)
{
    int n = *amb_count; if (n > AMB_CAP) n = AMB_CAP;
    const int i = blockIdx.y;
    if (i >= n) return;
    const int tid = threadIdx.x;
    const int jl = tid & 63;
    const int ks = tid >> 6;
    const int j = blockIdx.x * 64 + jl;
    const int grow = amb_grow[i];

    __shared__ float xs[768];
    __shared__ double ps[4][64];
    for (int t = tid; t < 768; t += 256) xs[t] = x[(size_t)grow * 768 + t];
    __syncthreads();

    double a0 = 0.0, a1 = 0.0;
    const float* wp = Wq + j;
    const int k0 = ks * 192;
#pragma unroll 8
    for (int k = 0; k < 192; k += 2) {
        a0 = fma((double)xs[k0 + k],     (double)wp[(size_t)(k0 + k) * 768],     a0);
        a1 = fma((double)xs[k0 + k + 1], (double)wp[(size_t)(k0 + k + 1) * 768], a1);
    }
    ps[ks][jl] = a0 + a1;
    __syncthreads();
    if (ks == 0)
        q64buf[(size_t)i * 768 + j] =
            ((ps[0][jl] + ps[1][jl]) + (ps[2][jl] + ps[3][jl])) + (double)bq[j];
}

__global__ __launch_bounds__(256) void fixB(
    const int* __restrict__ amb_count,
    const float* __restrict__ WkT, const float* __restrict__ bk,
    const double* __restrict__ q64buf,
    double* __restrict__ ubuf, double* __restrict__ bkqbuf)
{
    int n = *amb_count; if (n > AMB_CAP) n = AMB_CAP;
    const int i = blockIdx.y;
    if (i >= n) return;
    const int tid = threadIdx.x;
    const int tl = tid & 63;
    const int js = tid >> 6;
    const int t = blockIdx.x * 64 + tl;

    __shared__ double qs[768];
    __shared__ double ps[4][64];
    const double* qrow = q64buf + (size_t)i * 768;
    for (int k = tid; k < 768; k += 256) qs[k] = qrow[k];
    __syncthreads();

    double a0 = 0.0, a1 = 0.0;
    const float* wp = WkT + t;
    const int j0 = js * 192;
#pragma unroll 8
    for (int k = 0; k < 192; k += 2) {
        a0 = fma((double)wp[(size_t)(j0 + k) * 768],     qs[j0 + k],     a0);
        a1 = fma((double)wp[(size_t)(j0 + k + 1) * 768], qs[j0 + k + 1], a1);
    }
    ps[js][tl] = a0 + a1;
    __syncthreads();
    if (js == 0)
        ubuf[(size_t)i * 768 + t] = (ps[0][tl] + ps[1][tl]) + (ps[2][tl] + ps[3][tl]);

    if (blockIdx.x == 0 && tid < 64) {
        double p = 0.0;
#pragma unroll
        for (int c = 0; c < 12; ++c) {
            int jj = tid + (c << 6);
            p = fma((double)bk[jj], qs[jj], p);
        }
#pragma unroll
        for (int off = 32; off; off >>= 1) p += __shfl_xor(p, off);
        if (tid == 0) bkqbuf[i] = p;
    }
}

__global__ __launch_bounds__(256) void fixC(
    const int* __restrict__ amb_count, const int* __restrict__ amb_grow,
    const float* __restrict__ x, const float* __restrict__ pm,
    const int* __restrict__ cand, const float* __restrict__ oldw,
    const double* __restrict__ ubuf, const double* __restrict__ bkqbuf,
    const f16* __restrict__ vsave, float* __restrict__ dret)
{
    int n = *amb_count; if (n > AMB_CAP) n = AMB_CAP;
    const int i = blockIdx.x;
    if (i >= n) return;
    const int tid = threadIdx.x;
    const int lane = tid & 63;
    const int wave = tid >> 6;
    const int grow = amb_grow[i];
    const float* xb = x + (size_t)(grow >> 12) * TT * 768;

    __shared__ double us[768];
    __shared__ double cs_s[16];
    __shared__ float coef[16];

    const double* urow = ubuf + (size_t)i * 768;
    for (int t = tid; t < 768; t += 256) us[t] = urow[t];
    __syncthreads();

    const double ISQ = 1.0 / sqrt((double)DD);
    const double bkq = bkqbuf[i];
#pragma unroll
    for (int c = wave; c < 16; c += 4) {
        int s = cand[i * 16 + c];
        double p = 0.0;
        if (s < SS) {
            const float* xr = xb + (size_t)(4 * s) * 768;
#pragma unroll
            for (int t = 0; t < 12; ++t) {
                int j2 = lane + (t << 6);
                double sv = 0.25 * ((double)xr[j2] + (double)xr[j2 + 768] +
                                    (double)xr[j2 + 1536] + (double)xr[j2 + 2304]);
                p = fma(sv, us[j2], p);
            }
        } else {
            const float* pr = pm + (size_t)(s - SS) * 768;
#pragma unroll
            for (int t = 0; t < 12; ++t) {
                int j2 = lane + (t << 6);
                p = fma((double)pr[j2], us[j2], p);
            }
        }
#pragma unroll
        for (int off = 32; off; off >>= 1) p += __shfl_xor(p, off);
        if (lane == 0) cs_s[c] = (p + bkq) * ISQ;
    }
    __syncthreads();

    if (tid == 0) {
        double cs[16]; int ci[16];
        for (int c = 0; c < 16; ++c) { cs[c] = cs_s[c]; ci[c] = cand[i * 16 + c]; }
        unsigned used = 0;
        double sv[KTOP]; int sp[KTOP];
        for (int r = 0; r < KTOP; ++r) {
            int bi = -1;
            for (int c = 0; c < 16; ++c) {
                if (used & (1u << c)) continue;
                if (bi < 0 || cs[c] > cs[bi] ||
                    (cs[c] == cs[bi] && ci[c] < ci[bi])) bi = c;
            }
            used |= (1u << bi); sv[r] = cs[bi]; sp[r] = bi;
        }
        double mx = sv[0], es[KTOP], ssum = 0.0;
        for (int r = 0; r < KTOP; ++r) { es[r] = exp(sv[r] - mx); ssum += es[r]; }
        for (int c = 0; c < 16; ++c) coef[c] = (c < KTOP) ? -oldw[i * KTOP + c] : 0.f;
        for (int r = 0; r < KTOP; ++r) coef[sp[r]] += (float)(es[r] / ssum);
    }
    __syncthreads();

    const f16* vs = vsave + (size_t)i * 16 * 768;
    for (int j = tid; j < 768; j += 256) {
        float d = 0.f;
#pragma unroll
        for (int c = 0; c < 16; ++c) d += coef[c] * (float)vs[(size_t)c * 768 + j];
        dret[(size_t)i * 768 + j] = d;
    }
}

__global__ __launch_bounds__(256) void fixD(
    const int* __restrict__ amb_count, const int* __restrict__ amb_grow,
    const float* __restrict__ dret, const float* __restrict__ Wp,
    float* __restrict__ out)
{
    int n = *amb_count; if (n > AMB_CAP) n = AMB_CAP;
    const int i = blockIdx.y;
    if (i >= n) return;
    const int tid = threadIdx.x;
    const int jl = tid & 63;
    const int ks = tid >> 6;
    const int j = blockIdx.x * 64 + jl;
    const int grow = amb_grow[i];

    __shared__ float ds[768];
    __shared__ float ps[4][64];
    for (int t = tid; t < 768; t += 256) ds[t] = dret[(size_t)i * 768 + t];
    __syncthreads();

    float a0 = 0.f, a1 = 0.f;
    const float* wp = Wp + j;
    const int k0 = ks * 192;
#pragma unroll 8
    for (int k = 0; k < 192; k += 2) {
        a0 = fmaf(ds[k0 + k],     wp[(size_t)(k0 + k) * 768],     a0);
        a1 = fmaf(ds[k0 + k + 1], wp[(size_t)(k0 + k + 1) * 768], a1);
    }
    ps[ks][jl] = a0 + a1;
    __syncthreads();
    if (ks == 0)
        out[(size_t)grow * 768 + j] +=
            RWEIGHT * ((ps[0][jl] + ps[1][jl]) + (ps[2][jl] + ps[3][jl]));
}

// ---------------------------------------------------------------------------
extern "C" void kernel_launch(void* const* d_in, const int* in_sizes, int n_in,
                              void* d_out, int out_size, void* d_ws, size_t ws_size,
                              hipStream_t stream)
{
    const float* x  = (const float*)d_in[0];
    const float* Wq = (const float*)d_in[1];
    const float* bq = (const float*)d_in[2];
    const float* Wk = (const float*)d_in[3];
    const float* bk = (const float*)d_in[4];
    const float* Wv = (const float*)d_in[5];
    const float* bv = (const float*)d_in[6];
    const float* Wp = (const float*)d_in[7];
    const float* bp = (const float*)d_in[8];
    const float* pm = (const float*)d_in[9];
    float* out = (float*)d_out;
    float* ws  = (float*)d_ws;

    const float inv_sqrt_d = (float)(1.0 / sqrt((double)DD));
    const size_t TD  = (size_t)TT * DD;
    const size_t SD  = (size_t)SS * DD;
    const size_t WSZ = (size_t)DD * DD;

    float* p = ws;
    f16* WQh = (f16*)p; p += WSZ / 2;
    f16* WQm = (f16*)p; p += WSZ / 2;
    f16* WKh = (f16*)p; p += WSZ / 2;
    f16* WKm = (f16*)p; p += WSZ / 2;
    f16* WVh = (f16*)p; p += WSZ / 2;
    f16* WPh = (f16*)p; p += WSZ / 2;
    float* WkT32 = p; p += WSZ;
    float* slots_all = p; p += (size_t)BB * SD;
    f16* qh = (f16*)p; p += TD / 2;
    f16* qm = (f16*)p; p += TD / 2;
    f16* kh = (f16*)p; p += SD;             // [2S][768] f16 row-major
    f16* km = (f16*)p; p += SD;
    f16* v16a = (f16*)p; p += SD;
    f16* v16b = (f16*)p; p += SD;
    f16* retrA = (f16*)p; p += TD / 2;
    f16* retrB = (f16*)p; p += TD / 2;
    double* q64buf = (double*)p; p += (size_t)AMB_CAP * DD * 2;
    double* ubuf   = (double*)p; p += (size_t)AMB_CAP * DD * 2;
    double* bkqbuf = (double*)p; p += AMB_CAP * 2;
    int* cand = (int*)p; p += (size_t)AMB_CAP * 16;
    float* oldw = p; p += (size_t)AMB_CAP * KTOP;
    f16* vsave = (f16*)p; p += (size_t)AMB_CAP * 16 * DD / 2;
    float* dret = p; p += (size_t)AMB_CAP * DD;
    int* ambc = (int*)p; p += 64;
    int* ambgrow = (int*)p; p += AMB_CAP;
    float* scores = p;                      // [4096][2048]

    transpose_split<<<dim3(24, 24, 4), 256, 0, stream>>>(
        Wq, Wk, Wv, Wp, WQh, WQm, WKh, WKm, WVh, WPh, WkT32);
    zeroN<<<1, 64, 0, stream>>>(ambc);
    build_pooled_all<<<(BB * SS * DD) / 256, 256, 0, stream>>>(x, slots_all);

    // L0: producers for batch 0 + pm halves (k once; v pm into both bufs).
    megaSelProd<<<432, 256, 0, stream>>>(
        0, nullptr, nullptr, nullptr, 0, ambc, ambgrow, cand, oldw, vsave,
        1, 1, 1, x, slots_all, pm,
        WQh, WQm, WKh, WKm, WVh, bq, bk, bv, qh, qm, kh, km, v16a, v16b);
    // M0: scores(0).
    megaScoresProj<<<512, 256, 0, stream>>>(
        512, qh, qm, kh, km, scores, inv_sqrt_d, nullptr, WPh, bp, nullptr);

    for (int b = 1; b < BB; ++b) {
        f16* v16w = (b & 1) ? v16b : v16a;       // P(b) writes
        f16* v16r = ((b - 1) & 1) ? v16b : v16a; // C(b-1) reads
        f16* retrW = ((b - 1) & 1) ? retrB : retrA;

        // L(b): producers(b) tiles | select(b-1)
        megaSelProd<<<1312, 256, 0, stream>>>(
            1024, scores, v16r, retrW, (b - 1) * TT,
            ambc, ambgrow, cand, oldw, vsave,
            1, 1, 0, x + (size_t)b * TD, slots_all + (size_t)b * SD, nullptr,
            WQh, WQm, WKh, WKm, WVh, bq, bk, bv, qh, qm, kh, km, v16w, nullptr);
        // M(b): scores(b) | proj(b-1)
        megaScoresProj<<<704, 256, 0, stream>>>(
            512, qh, qm, kh, km, scores, inv_sqrt_d,
            retrW, WPh, bp, out + (size_t)(b - 1) * TD);
    }

    // L4: select(3) only.
    f16* v16r3 = v16b;           // (3&1) -> v16b
    f16* retrW3 = retrB;
    megaSelProd<<<1024, 256, 0, stream>>>(
        1024, scores, v16r3, retrW3, 3 * TT,
        ambc, ambgrow, cand, oldw, vsave,
        0, 0, 0, nullptr, nullptr, nullptr,
        WQh, WQm, WKh, WKm, WVh, bq, bk, bv, qh, qm, kh, km, nullptr, nullptr);
    // M4: proj(3) only.
    megaScoresProj<<<192, 256, 0, stream>>>(
        0, nullptr, nullptr, nullptr, nullptr, nullptr, 0.f,
        retrW3, WPh, bp, out + (size_t)3 * TD);

    // deferred exact fixups.
    fixA<<<dim3(12, AMB_CAP), 256, 0, stream>>>(ambc, ambgrow, x, Wq, bq, q64buf);
    fixB<<<dim3(12, AMB_CAP), 256, 0, stream>>>(ambc, WkT32, bk, q64buf, ubuf, bkqbuf);
    fixC<<<AMB_CAP, 256, 0, stream>>>(ambc, ambgrow, x, pm, cand, oldw,
                                      ubuf, bkqbuf, vsave, dret);
    fixD<<<dim3(12, AMB_CAP), 256, 0, stream>>>(ambc, ambgrow, dret, Wp, out);
}

// Round 20
// 606.737 us; speedup vs baseline: 1.0941x; 1.0236x over previous
//
#include <hip/hip_runtime.h>
#include <math.h>

#define BB 4
#define TT 4096
#define DD 768
#define SS 1024
#define S2 2048
#define KTOP 8
#define RWEIGHT 0.1f
#define TAU 2e-4f
#define AMB_CAP 256

typedef __attribute__((ext_vector_type(8))) _Float16 f16x8;
typedef __attribute__((ext_vector_type(4))) float f32x4;
typedef _Float16 f16;

// ---------------------------------------------------------------------------
__global__ __launch_bounds__(256) void build_pooled_all(
    const float* __restrict__ x, float* __restrict__ slots)
{
    int i = blockIdx.x * 256 + threadIdx.x;     // over B*S*D = 3145728
    int s2 = i / DD;
    int d = i - s2 * DD;
    int b = s2 >> 10, s = s2 & 1023;
    const float* xb = x + (size_t)b * TT * DD + (size_t)(4 * s) * DD + d;
    slots[i] = 0.25f * (xb[0] + xb[DD] + xb[2 * DD] + xb[3 * DD]);
}

// ---------------------------------------------------------------------------
// transpose_split: W^T as f16 h/m planes + f32 WkT (fixB, coalesced).
// ---------------------------------------------------------------------------
__global__ __launch_bounds__(256) void transpose_split(
    const float* __restrict__ W0, const float* __restrict__ W1,
    const float* __restrict__ W2, const float* __restrict__ W3,
    f16* __restrict__ WQh, f16* __restrict__ WQm,
    f16* __restrict__ WKh, f16* __restrict__ WKm,
    f16* __restrict__ WVh, f16* __restrict__ WPh,
    float* __restrict__ WkT32)
{
    const int z = blockIdx.z;
    const float* W = (z == 0) ? W0 : (z == 1) ? W1 : (z == 2) ? W2 : W3;
    __shared__ float t[32][33];
    int bx = blockIdx.x * 32, by = blockIdx.y * 32;
    int lx = threadIdx.x & 31, ly = threadIdx.x >> 5;
#pragma unroll
    for (int r = 0; r < 32; r += 8)
        t[ly + r][lx] = W[(size_t)(bx + ly + r) * 768 + by + lx];
    __syncthreads();
#pragma unroll
    for (int r = 0; r < 32; r += 8) {
        float w = t[lx][ly + r];
        size_t idx = (size_t)(by + ly + r) * 768 + bx + lx;
        f16 h = (f16)w;
        if (z == 0) { WQh[idx] = h; WQm[idx] = (f16)(w - (float)h); }
        else if (z == 1) { WKh[idx] = h; WKm[idx] = (f16)(w - (float)h); WkT32[idx] = w; }
        else if (z == 2) { WVh[idx] = h; }
        else { WPh[idx] = h; }
    }
}

__global__ void zeroN(int* p) { p[threadIdx.x] = 0; }

// ---------------------------------------------------------------------------
// Tile bodies with register-prefetch pipeline:
//   preload(k=0); loop { sync; stage(regs); sync; load(k+32); frag+mfma }
// Staging swizzle (verified r8): p(c,r)=c^(r&3)^((r>>2)&1);
// csw = ((l>>4)^(l&3)^((l>>2)&1))*8.
// ---------------------------------------------------------------------------
// 3-pass split producer (q,k): A f32 split in-kernel, B presplit planes.
__device__ __forceinline__ void tile_split_prod(
    const float* __restrict__ A, int arow0,
    const f16* __restrict__ Bh, const f16* __restrict__ Bm, int bncol,
    const float* __restrict__ bias,
    f16* __restrict__ Ch, f16* __restrict__ Cm, int crow0,
    f16* LAh, f16* LAm, f16* LBh, f16* LBm)
{
    const int tid = threadIdx.x;
    const int lane = tid & 63;
    const int wc = (tid >> 6) & 1;
    const int wr = (tid >> 7) & 1;
    const int srow = tid >> 1, c0 = tid & 1;
    const int p0 = c0 ^ (srow & 3) ^ ((srow >> 2) & 1);
    const int wo0 = srow * 32 + p0 * 8, wo1 = wo0 ^ 16;
    const int csw = (((lane >> 4) ^ (lane & 3) ^ ((lane >> 2) & 1)) * 8);

    f32x4 acc[4][4];
#pragma unroll
    for (int i = 0; i < 4; ++i)
#pragma unroll
        for (int j = 0; j < 4; ++j) acc[i][j] = (f32x4){0.f, 0.f, 0.f, 0.f};

    const float* pa = A + (size_t)(arow0 + srow) * 768 + c0 * 8;
    const f16* pbh = Bh + ((size_t)bncol + srow) * 768 + c0 * 8;
    const f16* pbm = Bm + ((size_t)bncol + srow) * 768 + c0 * 8;

    float4 a0 = *(const float4*)(pa);
    float4 a1 = *(const float4*)(pa + 4);
    float4 a2 = *(const float4*)(pa + 16);
    float4 a3 = *(const float4*)(pa + 20);
    f16x8 bh0 = *(const f16x8*)(pbh);
    f16x8 bh1 = *(const f16x8*)(pbh + 16);
    f16x8 bm0 = *(const f16x8*)(pbm);
    f16x8 bm1 = *(const f16x8*)(pbm + 16);

    for (int k0 = 0; k0 < 768; k0 += 32) {
        __syncthreads();
        {
            float av[16] = {a0.x, a0.y, a0.z, a0.w, a1.x, a1.y, a1.z, a1.w,
                            a2.x, a2.y, a2.z, a2.w, a3.x, a3.y, a3.z, a3.w};
            f16x8 h, m;
#pragma unroll
            for (int j = 0; j < 8; ++j) {
                f16 hh = (f16)av[j]; h[j] = hh; m[j] = (f16)(av[j] - (float)hh);
            }
            *(f16x8*)&LAh[wo0] = h; *(f16x8*)&LAm[wo0] = m;
#pragma unroll
            for (int j = 0; j < 8; ++j) {
                f16 hh = (f16)av[j + 8]; h[j] = hh; m[j] = (f16)(av[j + 8] - (float)hh);
            }
            *(f16x8*)&LAh[wo1] = h; *(f16x8*)&LAm[wo1] = m;
            *(f16x8*)&LBh[wo0] = bh0; *(f16x8*)&LBh[wo1] = bh1;
            *(f16x8*)&LBm[wo0] = bm0; *(f16x8*)&LBm[wo1] = bm1;
        }
        __syncthreads();

        if (k0 + 32 < 768) {                  // prefetch next k-step
            a0 = *(const float4*)(pa + k0 + 32);
            a1 = *(const float4*)(pa + k0 + 36);
            a2 = *(const float4*)(pa + k0 + 48);
            a3 = *(const float4*)(pa + k0 + 52);
            bh0 = *(const f16x8*)(pbh + k0 + 32);
            bh1 = *(const f16x8*)(pbh + k0 + 48);
            bm0 = *(const f16x8*)(pbm + k0 + 32);
            bm1 = *(const f16x8*)(pbm + k0 + 48);
        }

        f16x8 fah[4], fam[4], fbh[4], fbm[4];
#pragma unroll
        for (int mi = 0; mi < 4; ++mi) {
            int off = (wr * 64 + mi * 16 + (lane & 15)) * 32 + csw;
            fah[mi] = *(const f16x8*)&LAh[off];
            fam[mi] = *(const f16x8*)&LAm[off];
        }
#pragma unroll
        for (int ni = 0; ni < 4; ++ni) {
            int off = (wc * 64 + ni * 16 + (lane & 15)) * 32 + csw;
            fbh[ni] = *(const f16x8*)&LBh[off];
            fbm[ni] = *(const f16x8*)&LBm[off];
        }
#pragma unroll
        for (int mi = 0; mi < 4; ++mi)
#pragma unroll
            for (int ni = 0; ni < 4; ++ni) {
                acc[mi][ni] = __builtin_amdgcn_mfma_f32_16x16x32_f16(
                    fah[mi], fbh[ni], acc[mi][ni], 0, 0, 0);
                acc[mi][ni] = __builtin_amdgcn_mfma_f32_16x16x32_f16(
                    fah[mi], fbm[ni], acc[mi][ni], 0, 0, 0);
                acc[mi][ni] = __builtin_amdgcn_mfma_f32_16x16x32_f16(
                    fam[mi], fbh[ni], acc[mi][ni], 0, 0, 0);
            }
    }

    const int orow0 = wr * 64 + (lane >> 4) * 4;
    const int ocol0 = wc * 64 + (lane & 15);
#pragma unroll
    for (int mi = 0; mi < 4; ++mi)
#pragma unroll
        for (int ni = 0; ni < 4; ++ni) {
            size_t col = (size_t)bncol + ocol0 + ni * 16;
            float badd = bias[col];
            size_t rbase = (size_t)crow0 + orow0 + mi * 16;
#pragma unroll
            for (int r = 0; r < 4; ++r) {
                float val = acc[mi][ni][r] + badd;
                f16 h = (f16)val;
                size_t idx = (rbase + r) * 768 + col;
                Ch[idx] = h;
                Cm[idx] = (f16)(val - (float)h);
            }
        }
}

// 1-pass producer (v): A f32 h-convert, B f16 plane copy.
__device__ __forceinline__ void tile_1p_prod(
    const float* __restrict__ A, int arow0,
    const f16* __restrict__ Bh, int bncol,
    const float* __restrict__ bias,
    f16* __restrict__ Co, int crow0, f16* LA, f16* LB)
{
    const int tid = threadIdx.x;
    const int lane = tid & 63;
    const int wc = (tid >> 6) & 1;
    const int wr = (tid >> 7) & 1;
    const int srow = tid >> 1, c0 = tid & 1;
    const int p0 = c0 ^ (srow & 3) ^ ((srow >> 2) & 1);
    const int wo0 = srow * 32 + p0 * 8, wo1 = wo0 ^ 16;
    const int csw = (((lane >> 4) ^ (lane & 3) ^ ((lane >> 2) & 1)) * 8);

    f32x4 acc[4][4];
#pragma unroll
    for (int i = 0; i < 4; ++i)
#pragma unroll
        for (int j = 0; j < 4; ++j) acc[i][j] = (f32x4){0.f, 0.f, 0.f, 0.f};

    const float* pa = A + (size_t)(arow0 + srow) * 768 + c0 * 8;
    const f16* pbh = Bh + ((size_t)bncol + srow) * 768 + c0 * 8;

    float4 a0 = *(const float4*)(pa);
    float4 a1 = *(const float4*)(pa + 4);
    float4 a2 = *(const float4*)(pa + 16);
    float4 a3 = *(const float4*)(pa + 20);
    f16x8 bh0 = *(const f16x8*)(pbh);
    f16x8 bh1 = *(const f16x8*)(pbh + 16);

    for (int k0 = 0; k0 < 768; k0 += 32) {
        __syncthreads();
        {
            f16x8 h;
            h[0] = (f16)a0.x; h[1] = (f16)a0.y; h[2] = (f16)a0.z; h[3] = (f16)a0.w;
            h[4] = (f16)a1.x; h[5] = (f16)a1.y; h[6] = (f16)a1.z; h[7] = (f16)a1.w;
            *(f16x8*)&LA[wo0] = h;
            h[0] = (f16)a2.x; h[1] = (f16)a2.y; h[2] = (f16)a2.z; h[3] = (f16)a2.w;
            h[4] = (f16)a3.x; h[5] = (f16)a3.y; h[6] = (f16)a3.z; h[7] = (f16)a3.w;
            *(f16x8*)&LA[wo1] = h;
            *(f16x8*)&LB[wo0] = bh0;
            *(f16x8*)&LB[wo1] = bh1;
        }
        __syncthreads();

        if (k0 + 32 < 768) {
            a0 = *(const float4*)(pa + k0 + 32);
            a1 = *(const float4*)(pa + k0 + 36);
            a2 = *(const float4*)(pa + k0 + 48);
            a3 = *(const float4*)(pa + k0 + 52);
            bh0 = *(const f16x8*)(pbh + k0 + 32);
            bh1 = *(const f16x8*)(pbh + k0 + 48);
        }

        f16x8 fah[4], fbh[4];
#pragma unroll
        for (int mi = 0; mi < 4; ++mi)
            fah[mi] = *(const f16x8*)&LA[(wr * 64 + mi * 16 + (lane & 15)) * 32 + csw];
#pragma unroll
        for (int ni = 0; ni < 4; ++ni)
            fbh[ni] = *(const f16x8*)&LB[(wc * 64 + ni * 16 + (lane & 15)) * 32 + csw];
#pragma unroll
        for (int mi = 0; mi < 4; ++mi)
#pragma unroll
            for (int ni = 0; ni < 4; ++ni)
                acc[mi][ni] = __builtin_amdgcn_mfma_f32_16x16x32_f16(
                    fah[mi], fbh[ni], acc[mi][ni], 0, 0, 0);
    }

    const int orow0 = wr * 64 + (lane >> 4) * 4;
    const int ocol0 = wc * 64 + (lane & 15);
#pragma unroll
    for (int mi = 0; mi < 4; ++mi)
#pragma unroll
        for (int ni = 0; ni < 4; ++ni) {
            size_t col = (size_t)bncol + ocol0 + ni * 16;
            float badd = bias[col];
            size_t rbase = (size_t)crow0 + orow0 + mi * 16;
#pragma unroll
            for (int r = 0; r < 4; ++r)
                Co[(rbase + r) * 768 + col] = (f16)(acc[mi][ni][r] + badd);
        }
}

// proj: A f16 copy, B f16 plane copy, f32 out scaled by RWEIGHT.
__device__ __forceinline__ void tile_proj(
    const f16* __restrict__ A, int arow0,
    const f16* __restrict__ Bh, int bncol,
    const float* __restrict__ bias,
    float* __restrict__ Co, int crow0, f16* LA, f16* LB)
{
    const int tid = threadIdx.x;
    const int lane = tid & 63;
    const int wc = (tid >> 6) & 1;
    const int wr = (tid >> 7) & 1;
    const int srow = tid >> 1, c0 = tid & 1;
    const int p0 = c0 ^ (srow & 3) ^ ((srow >> 2) & 1);
    const int wo0 = srow * 32 + p0 * 8, wo1 = wo0 ^ 16;
    const int csw = (((lane >> 4) ^ (lane & 3) ^ ((lane >> 2) & 1)) * 8);

    f32x4 acc[4][4];
#pragma unroll
    for (int i = 0; i < 4; ++i)
#pragma unroll
        for (int j = 0; j < 4; ++j) acc[i][j] = (f32x4){0.f, 0.f, 0.f, 0.f};

    const f16* pa = A + (size_t)(arow0 + srow) * 768 + c0 * 8;
    const f16* pbh = Bh + ((size_t)bncol + srow) * 768 + c0 * 8;

    f16x8 ah0 = *(const f16x8*)(pa);
    f16x8 ah1 = *(const f16x8*)(pa + 16);
    f16x8 bh0 = *(const f16x8*)(pbh);
    f16x8 bh1 = *(const f16x8*)(pbh + 16);

    for (int k0 = 0; k0 < 768; k0 += 32) {
        __syncthreads();
        *(f16x8*)&LA[wo0] = ah0; *(f16x8*)&LA[wo1] = ah1;
        *(f16x8*)&LB[wo0] = bh0; *(f16x8*)&LB[wo1] = bh1;
        __syncthreads();

        if (k0 + 32 < 768) {
            ah0 = *(const f16x8*)(pa + k0 + 32);
            ah1 = *(const f16x8*)(pa + k0 + 48);
            bh0 = *(const f16x8*)(pbh + k0 + 32);
            bh1 = *(const f16x8*)(pbh + k0 + 48);
        }

        f16x8 fah[4], fbh[4];
#pragma unroll
        for (int mi = 0; mi < 4; ++mi)
            fah[mi] = *(const f16x8*)&LA[(wr * 64 + mi * 16 + (lane & 15)) * 32 + csw];
#pragma unroll
        for (int ni = 0; ni < 4; ++ni)
            fbh[ni] = *(const f16x8*)&LB[(wc * 64 + ni * 16 + (lane & 15)) * 32 + csw];
#pragma unroll
        for (int mi = 0; mi < 4; ++mi)
#pragma unroll
            for (int ni = 0; ni < 4; ++ni)
                acc[mi][ni] = __builtin_amdgcn_mfma_f32_16x16x32_f16(
                    fah[mi], fbh[ni], acc[mi][ni], 0, 0, 0);
    }

    const int orow0 = wr * 64 + (lane >> 4) * 4;
    const int ocol0 = wc * 64 + (lane & 15);
#pragma unroll
    for (int mi = 0; mi < 4; ++mi)
#pragma unroll
        for (int ni = 0; ni < 4; ++ni) {
            size_t col = (size_t)bncol + ocol0 + ni * 16;
            float badd = RWEIGHT * bias[col];
            size_t rbase = (size_t)crow0 + orow0 + mi * 16;
#pragma unroll
            for (int r = 0; r < 4; ++r)
                Co[(rbase + r) * 768 + col] = RWEIGHT * acc[mi][ni][r] + badd;
        }
}

// 3-pass scores from h/m planes (pure 16B f16 staging + reg prefetch).
__device__ __forceinline__ void tile_scores_planes(
    const f16* __restrict__ qh, const f16* __restrict__ qm, int arow0,
    const f16* __restrict__ kh, const f16* __restrict__ km, int bncol,
    float* __restrict__ C, float alpha,
    f16* LAh, f16* LAm, f16* LBh, f16* LBm)
{
    const int tid = threadIdx.x;
    const int lane = tid & 63;
    const int wc = (tid >> 6) & 1;
    const int wr = (tid >> 7) & 1;
    const int srow = tid >> 1, c0 = tid & 1;
    const int p0 = c0 ^ (srow & 3) ^ ((srow >> 2) & 1);
    const int wo0 = srow * 32 + p0 * 8, wo1 = wo0 ^ 16;
    const int csw = (((lane >> 4) ^ (lane & 3) ^ ((lane >> 2) & 1)) * 8);
    const size_t bn = (size_t)bncol;

    f32x4 acc[4][4];
#pragma unroll
    for (int i = 0; i < 4; ++i)
#pragma unroll
        for (int j = 0; j < 4; ++j) acc[i][j] = (f32x4){0.f, 0.f, 0.f, 0.f};

    const f16* pah = qh + (size_t)(arow0 + srow) * 768 + c0 * 8;
    const f16* pam = qm + (size_t)(arow0 + srow) * 768 + c0 * 8;
    const f16* pbh = kh + (bn + srow) * 768 + c0 * 8;
    const f16* pbm = km + (bn + srow) * 768 + c0 * 8;

    f16x8 ah0 = *(const f16x8*)(pah);
    f16x8 ah1 = *(const f16x8*)(pah + 16);
    f16x8 am0 = *(const f16x8*)(pam);
    f16x8 am1 = *(const f16x8*)(pam + 16);
    f16x8 bh0 = *(const f16x8*)(pbh);
    f16x8 bh1 = *(const f16x8*)(pbh + 16);
    f16x8 bm0 = *(const f16x8*)(pbm);
    f16x8 bm1 = *(const f16x8*)(pbm + 16);

    for (int k0 = 0; k0 < 768; k0 += 32) {
        __syncthreads();
        *(f16x8*)&LAh[wo0] = ah0; *(f16x8*)&LAh[wo1] = ah1;
        *(f16x8*)&LAm[wo0] = am0; *(f16x8*)&LAm[wo1] = am1;
        *(f16x8*)&LBh[wo0] = bh0; *(f16x8*)&LBh[wo1] = bh1;
        *(f16x8*)&LBm[wo0] = bm0; *(f16x8*)&LBm[wo1] = bm1;
        __syncthreads();

        if (k0 + 32 < 768) {
            ah0 = *(const f16x8*)(pah + k0 + 32);
            ah1 = *(const f16x8*)(pah + k0 + 48);
            am0 = *(const f16x8*)(pam + k0 + 32);
            am1 = *(const f16x8*)(pam + k0 + 48);
            bh0 = *(const f16x8*)(pbh + k0 + 32);
            bh1 = *(const f16x8*)(pbh + k0 + 48);
            bm0 = *(const f16x8*)(pbm + k0 + 32);
            bm1 = *(const f16x8*)(pbm + k0 + 48);
        }

        f16x8 fah[4], fam[4], fbh[4], fbm[4];
#pragma unroll
        for (int mi = 0; mi < 4; ++mi) {
            int off = (wr * 64 + mi * 16 + (lane & 15)) * 32 + csw;
            fah[mi] = *(const f16x8*)&LAh[off];
            fam[mi] = *(const f16x8*)&LAm[off];
        }
#pragma unroll
        for (int ni = 0; ni < 4; ++ni) {
            int off = (wc * 64 + ni * 16 + (lane & 15)) * 32 + csw;
            fbh[ni] = *(const f16x8*)&LBh[off];
            fbm[ni] = *(const f16x8*)&LBm[off];
        }
#pragma unroll
        for (int mi = 0; mi < 4; ++mi)
#pragma unroll
            for (int ni = 0; ni < 4; ++ni) {
                acc[mi][ni] = __builtin_amdgcn_mfma_f32_16x16x32_f16(
                    fah[mi], fbh[ni], acc[mi][ni], 0, 0, 0);
                acc[mi][ni] = __builtin_amdgcn_mfma_f32_16x16x32_f16(
                    fah[mi], fbm[ni], acc[mi][ni], 0, 0, 0);
                acc[mi][ni] = __builtin_amdgcn_mfma_f32_16x16x32_f16(
                    fam[mi], fbh[ni], acc[mi][ni], 0, 0, 0);
            }
    }

    const int orow0 = wr * 64 + (lane >> 4) * 4;
    const int ocol0 = wc * 64 + (lane & 15);
#pragma unroll
    for (int mi = 0; mi < 4; ++mi)
#pragma unroll
        for (int ni = 0; ni < 4; ++ni) {
            size_t col = bn + ocol0 + ni * 16;
            size_t rbase = (size_t)arow0 + orow0 + mi * 16;
#pragma unroll
            for (int r = 0; r < 4; ++r)
                C[(rbase + r) * S2 + col] = alpha * acc[mi][ni][r];
        }
}

// ---------------------------------------------------------------------------
// megaSelProd: [q tiles | k tiles | v tiles | select rows of prev batch]
// ---------------------------------------------------------------------------
__global__ __launch_bounds__(256) void megaSelProd(
    int nSel, const float* __restrict__ scores, const f16* __restrict__ v16r,
    f16* __restrict__ retrW, int gbase,
    int* __restrict__ ambc, int* __restrict__ ambgrow, int* __restrict__ cand,
    float* __restrict__ oldw, f16* __restrict__ vsave,
    int hasQ, int hasKV, int doPm,
    const float* __restrict__ xq, const float* __restrict__ slots_b,
    const float* __restrict__ pm,
    const f16* __restrict__ WQh, const f16* __restrict__ WQm,
    const f16* __restrict__ WKh, const f16* __restrict__ WKm,
    const f16* __restrict__ WVh,
    const float* __restrict__ bq, const float* __restrict__ bk,
    const float* __restrict__ bv,
    f16* __restrict__ qh, f16* __restrict__ qm,
    f16* __restrict__ kh, f16* __restrict__ km,
    f16* __restrict__ v16w, f16* __restrict__ v16w2)
{
    __shared__ f16 LAh[4096], LAm[4096], LBh[4096], LBm[4096];
    int t = blockIdx.x;

    if (hasQ) {
        if (t < 192) {
            tile_split_prod(xq, (t / 6) * 128, WQh, WQm, (t % 6) * 128, bq,
                            qh, qm, (t / 6) * 128, LAh, LAm, LBh, LBm);
            return;
        }
        t -= 192;
    }
    if (hasKV) {
        if (t < 48) {
            tile_split_prod(slots_b, (t / 6) * 128, WKh, WKm, (t % 6) * 128, bk,
                            kh, km, (t / 6) * 128, LAh, LAm, LBh, LBm);
            return;
        }
        t -= 48;
        if (doPm) {
            if (t < 48) {
                tile_split_prod(pm, (t / 6) * 128, WKh, WKm, (t % 6) * 128, bk,
                                kh, km, 1024 + (t / 6) * 128, LAh, LAm, LBh, LBm);
                return;
            }
            t -= 48;
        }
        if (t < 48) {
            tile_1p_prod(slots_b, (t / 6) * 128, WVh, (t % 6) * 128, bv,
                         v16w, (t / 6) * 128, LAh, LBh);
            return;
        }
        t -= 48;
        if (doPm) {
            if (t < 48) {
                tile_1p_prod(pm, (t / 6) * 128, WVh, (t % 6) * 128, bv,
                             v16w, 1024 + (t / 6) * 128, LAh, LBh);
                return;
            }
            t -= 48;
            if (t < 48) {
                tile_1p_prod(pm, (t / 6) * 128, WVh, (t % 6) * 128, bv,
                             v16w2, 1024 + (t / 6) * 128, LAh, LBh);
                return;
            }
            t -= 48;
        }
    }
    if (t >= nSel) return;

    // ----- select_combine: one wave per row -----
    const int lane = threadIdx.x & 63;
    const int wave = threadIdx.x >> 6;
    const int row = t * 4 + wave;
    const float* srow = scores + (size_t)row * S2;
    float vals[32];
#pragma unroll
    for (int i = 0; i < 32; ++i) vals[i] = srow[lane + (i << 6)];

    float topv[16]; int topi[16];
    bool amb = false;
    int nr = 9;
    for (int r = 0; r < 16; ++r) {
        if (r >= nr) break;
        float bvv = -3.4e38f; int bii = 0x7fffffff;
#pragma unroll
        for (int i = 0; i < 32; ++i)
            if (vals[i] > bvv) { bvv = vals[i]; bii = lane + (i << 6); }
#pragma unroll
        for (int off = 32; off > 0; off >>= 1) {
            float ov = __shfl_xor(bvv, off);
            int   oi = __shfl_xor(bii, off);
            if (ov > bvv || (ov == bvv && oi < bii)) { bvv = ov; bii = oi; }
        }
        topv[r] = bvv; topi[r] = bii;
        if ((bii & 63) == lane) vals[bii >> 6] = -3.4e38f;
        if (r == 8) {
            amb = (topv[7] - topv[8]) < TAU;
            if (amb) nr = 16;
        }
    }

    float m = topv[0], w[KTOP], sum = 0.f;
#pragma unroll
    for (int r = 0; r < KTOP; ++r) { w[r] = expf(topv[r] - m); sum += w[r]; }
    float inv = 1.f / sum;
#pragma unroll
    for (int r = 0; r < KTOP; ++r) w[r] *= inv;

    if (amb) {
        int idx = 0;
        if (lane == 0) idx = atomicAdd(ambc, 1);
        idx = __shfl(idx, 0);
        if (idx < AMB_CAP) {
            if (lane == 0) ambgrow[idx] = gbase + row;
            if (lane < 16) cand[idx * 16 + lane] = topi[lane];
            if (lane < KTOP) oldw[idx * KTOP + lane] = w[lane];
            f16* vs = vsave + (size_t)idx * 16 * 768;
            for (int cc = lane; cc < 16 * 96; cc += 64) {
                int cr = cc / 96, ch = cc - cr * 96;
                *(f16x8*)&vs[(size_t)cr * 768 + ch * 8] =
                    *(const f16x8*)&v16r[(size_t)topi[cr] * 768 + ch * 8];
            }
        }
    }

    for (int c = lane; c < 96; c += 64) {
        float o[8] = {0, 0, 0, 0, 0, 0, 0, 0};
#pragma unroll
        for (int r = 0; r < KTOP; ++r) {
            f16x8 vv = *(const f16x8*)&v16r[(size_t)topi[r] * 768 + c * 8];
#pragma unroll
            for (int j = 0; j < 8; ++j) o[j] += w[r] * (float)vv[j];
        }
        f16x8 hx;
#pragma unroll
        for (int j = 0; j < 8; ++j) hx[j] = (f16)o[j];
        *(f16x8*)&retrW[(size_t)row * 768 + c * 8] = hx;
    }
}

// ---------------------------------------------------------------------------
// megaScoresProj: [scores tiles (3-pass planes) | proj tiles of prev batch]
// ---------------------------------------------------------------------------
__global__ __launch_bounds__(256) void megaScoresProj(
    int nSc, const f16* __restrict__ qh, const f16* __restrict__ qm,
    const f16* __restrict__ kh, const f16* __restrict__ km,
    float* __restrict__ scores, float alpha,
    const f16* __restrict__ retrR, const f16* __restrict__ WPh,
    const float* __restrict__ bp, float* __restrict__ outp)
{
    __shared__ f16 LAh[4096], LAm[4096], LBh[4096], LBm[4096];
    int t = blockIdx.x;
    if (t < nSc) {
        tile_scores_planes(qh, qm, (t >> 4) * 128, kh, km, (t & 15) * 128,
                           scores, alpha, LAh, LAm, LBh, LBm);
        return;
    }
    t -= nSc;
    tile_proj(retrR, (t / 6) * 128, WPh, (t % 6) * 128, bp,
              outp, (t / 6) * 128, LAh, LBh);
}

// ---------------------------------------------------------------------------
// Deferred exact fixups (post-loop, applied to out). Validated r10/r12/r15.
// ---------------------------------------------------------------------------
__global__ __launch_bounds__(256) void fixA(
    const int* __restrict__ amb_count, const int* __restrict__ amb_grow,
    const float* __restrict__ x, const float* __restrict__ Wq,
    const float* __restrict__ bq, double* __restrict__ q64buf)
{
    int n = *amb_count; if (n > AMB_CAP) n = AMB_CAP;
    const int i = blockIdx.y;
    if (i >= n) return;
    const int tid = threadIdx.x;
    const int jl = tid & 63;
    const int ks = tid >> 6;
    const int j = blockIdx.x * 64 + jl;
    const int grow = amb_grow[i];

    __shared__ float xs[768];
    __shared__ double ps[4][64];
    for (int t = tid; t < 768; t += 256) xs[t] = x[(size_t)grow * 768 + t];
    __syncthreads();

    double a0 = 0.0, a1 = 0.0;
    const float* wp = Wq + j;
    const int k0 = ks * 192;
#pragma unroll 8
    for (int k = 0; k < 192; k += 2) {
        a0 = fma((double)xs[k0 + k],     (double)wp[(size_t)(k0 + k) * 768],     a0);
        a1 = fma((double)xs[k0 + k + 1], (double)wp[(size_t)(k0 + k + 1) * 768], a1);
    }
    ps[ks][jl] = a0 + a1;
    __syncthreads();
    if (ks == 0)
        q64buf[(size_t)i * 768 + j] =
            ((ps[0][jl] + ps[1][jl]) + (ps[2][jl] + ps[3][jl])) + (double)bq[j];
}

__global__ __launch_bounds__(256) void fixB(
    const int* __restrict__ amb_count,
    const float* __restrict__ WkT, const float* __restrict__ bk,
    const double* __restrict__ q64buf,
    double* __restrict__ ubuf, double* __restrict__ bkqbuf)
{
    int n = *amb_count; if (n > AMB_CAP) n = AMB_CAP;
    const int i = blockIdx.y;
    if (i >= n) return;
    const int tid = threadIdx.x;
    const int tl = tid & 63;
    const int js = tid >> 6;
    const int t = blockIdx.x * 64 + tl;

    __shared__ double qs[768];
    __shared__ double ps[4][64];
    const double* qrow = q64buf + (size_t)i * 768;
    for (int k = tid; k < 768; k += 256) qs[k] = qrow[k];
    __syncthreads();

    double a0 = 0.0, a1 = 0.0;
    const float* wp = WkT + t;
    const int j0 = js * 192;
#pragma unroll 8
    for (int k = 0; k < 192; k += 2) {
        a0 = fma((double)wp[(size_t)(j0 + k) * 768],     qs[j0 + k],     a0);
        a1 = fma((double)wp[(size_t)(j0 + k + 1) * 768], qs[j0 + k + 1], a1);
    }
    ps[js][tl] = a0 + a1;
    __syncthreads();
    if (js == 0)
        ubuf[(size_t)i * 768 + t] = (ps[0][tl] + ps[1][tl]) + (ps[2][tl] + ps[3][tl]);

    if (blockIdx.x == 0 && tid < 64) {
        double p = 0.0;
#pragma unroll
        for (int c = 0; c < 12; ++c) {
            int jj = tid + (c << 6);
            p = fma((double)bk[jj], qs[jj], p);
        }
#pragma unroll
        for (int off = 32; off; off >>= 1) p += __shfl_xor(p, off);
        if (tid == 0) bkqbuf[i] = p;
    }
}

__global__ __launch_bounds__(256) void fixC(
    const int* __restrict__ amb_count, const int* __restrict__ amb_grow,
    const float* __restrict__ x, const float* __restrict__ pm,
    const int* __restrict__ cand, const float* __restrict__ oldw,
    const double* __restrict__ ubuf, const double* __restrict__ bkqbuf,
    const f16* __restrict__ vsave, float* __restrict__ dret)
{
    int n = *amb_count; if (n > AMB_CAP) n = AMB_CAP;
    const int i = blockIdx.x;
    if (i >= n) return;
    const int tid = threadIdx.x;
    const int lane = tid & 63;
    const int wave = tid >> 6;
    const int grow = amb_grow[i];
    const float* xb = x + (size_t)(grow >> 12) * TT * 768;

    __shared__ double us[768];
    __shared__ double cs_s[16];
    __shared__ float coef[16];

    const double* urow = ubuf + (size_t)i * 768;
    for (int t = tid; t < 768; t += 256) us[t] = urow[t];
    __syncthreads();

    const double ISQ = 1.0 / sqrt((double)DD);
    const double bkq = bkqbuf[i];
#pragma unroll
    for (int c = wave; c < 16; c += 4) {
        int s = cand[i * 16 + c];
        double p = 0.0;
        if (s < SS) {
            const float* xr = xb + (size_t)(4 * s) * 768;
#pragma unroll
            for (int t = 0; t < 12; ++t) {
                int j2 = lane + (t << 6);
                double sv = 0.25 * ((double)xr[j2] + (double)xr[j2 + 768] +
                                    (double)xr[j2 + 1536] + (double)xr[j2 + 2304]);
                p = fma(sv, us[j2], p);
            }
        } else {
            const float* pr = pm + (size_t)(s - SS) * 768;
#pragma unroll
            for (int t = 0; t < 12; ++t) {
                int j2 = lane + (t << 6);
                p = fma((double)pr[j2], us[j2], p);
            }
        }
#pragma unroll
        for (int off = 32; off; off >>= 1) p += __shfl_xor(p, off);
        if (lane == 0) cs_s[c] = (p + bkq) * ISQ;
    }
    __syncthreads();

    if (tid == 0) {
        double cs[16]; int ci[16];
        for (int c = 0; c < 16; ++c) { cs[c] = cs_s[c]; ci[c] = cand[i * 16 + c]; }
        unsigned used = 0;
        double sv[KTOP]; int sp[KTOP];
        for (int r = 0; r < KTOP; ++r) {
            int bi = -1;
            for (int c = 0; c < 16; ++c) {
                if (used & (1u << c)) continue;
                if (bi < 0 || cs[c] > cs[bi] ||
                    (cs[c] == cs[bi] && ci[c] < ci[bi])) bi = c;
            }
            used |= (1u << bi); sv[r] = cs[bi]; sp[r] = bi;
        }
        double mx = sv[0], es[KTOP], ssum = 0.0;
        for (int r = 0; r < KTOP; ++r) { es[r] = exp(sv[r] - mx); ssum += es[r]; }
        for (int c = 0; c < 16; ++c) coef[c] = (c < KTOP) ? -oldw[i * KTOP + c] : 0.f;
        for (int r = 0; r < KTOP; ++r) coef[sp[r]] += (float)(es[r] / ssum);
    }
    __syncthreads();

    const f16* vs = vsave + (size_t)i * 16 * 768;
    for (int j = tid; j < 768; j += 256) {
        float d = 0.f;
#pragma unroll
        for (int c = 0; c < 16; ++c) d += coef[c] * (float)vs[(size_t)c * 768 + j];
        dret[(size_t)i * 768 + j] = d;
    }
}

__global__ __launch_bounds__(256) void fixD(
    const int* __restrict__ amb_count, const int* __restrict__ amb_grow,
    const float* __restrict__ dret, const float* __restrict__ Wp,
    float* __restrict__ out)
{
    int n = *amb_count; if (n > AMB_CAP) n = AMB_CAP;
    const int i = blockIdx.y;
    if (i >= n) return;
    const int tid = threadIdx.x;
    const int jl = tid & 63;
    const int ks = tid >> 6;
    const int j = blockIdx.x * 64 + jl;
    const int grow = amb_grow[i];

    __shared__ float ds[768];
    __shared__ float ps[4][64];
    for (int t = tid; t < 768; t += 256) ds[t] = dret[(size_t)i * 768 + t];
    __syncthreads();

    float a0 = 0.f, a1 = 0.f;
    const float* wp = Wp + j;
    const int k0 = ks * 192;
#pragma unroll 8
    for (int k = 0; k < 192; k += 2) {
        a0 = fmaf(ds[k0 + k],     wp[(size_t)(k0 + k) * 768],     a0);
        a1 = fmaf(ds[k0 + k + 1], wp[(size_t)(k0 + k + 1) * 768], a1);
    }
    ps[ks][jl] = a0 + a1;
    __syncthreads();
    if (ks == 0)
        out[(size_t)grow * 768 + j] +=
            RWEIGHT * ((ps[0][jl] + ps[1][jl]) + (ps[2][jl] + ps[3][jl]));
}

// ---------------------------------------------------------------------------
extern "C" void kernel_launch(void* const* d_in, const int* in_sizes, int n_in,
                              void* d_out, int out_size, void* d_ws, size_t ws_size,
                              hipStream_t stream)
{
    const float* x  = (const float*)d_in[0];
    const float* Wq = (const float*)d_in[1];
    const float* bq = (const float*)d_in[2];
    const float* Wk = (const float*)d_in[3];
    const float* bk = (const float*)d_in[4];
    const float* Wv = (const float*)d_in[5];
    const float* bv = (const float*)d_in[6];
    const float* Wp = (const float*)d_in[7];
    const float* bp = (const float*)d_in[8];
    const float* pm = (const float*)d_in[9];
    float* out = (float*)d_out;
    float* ws  = (float*)d_ws;

    const float inv_sqrt_d = (float)(1.0 / sqrt((double)DD));
    const size_t TD  = (size_t)TT * DD;
    const size_t SD  = (size_t)SS * DD;
    const size_t WSZ = (size_t)DD * DD;

    float* p = ws;
    f16* WQh = (f16*)p; p += WSZ / 2;
    f16* WQm = (f16*)p; p += WSZ / 2;
    f16* WKh = (f16*)p; p += WSZ / 2;
    f16* WKm = (f16*)p; p += WSZ / 2;
    f16* WVh = (f16*)p; p += WSZ / 2;
    f16* WPh = (f16*)p; p += WSZ / 2;
    float* WkT32 = p; p += WSZ;
    float* slots_all = p; p += (size_t)BB * SD;
    f16* qh = (f16*)p; p += TD / 2;
    f16* qm = (f16*)p; p += TD / 2;
    f16* kh = (f16*)p; p += SD;             // [2S][768] f16 row-major
    f16* km = (f16*)p; p += SD;
    f16* v16a = (f16*)p; p += SD;
    f16* v16b = (f16*)p; p += SD;
    f16* retrA = (f16*)p; p += TD / 2;
    f16* retrB = (f16*)p; p += TD / 2;
    double* q64buf = (double*)p; p += (size_t)AMB_CAP * DD * 2;
    double* ubuf   = (double*)p; p += (size_t)AMB_CAP * DD * 2;
    double* bkqbuf = (double*)p; p += AMB_CAP * 2;
    int* cand = (int*)p; p += (size_t)AMB_CAP * 16;
    float* oldw = p; p += (size_t)AMB_CAP * KTOP;
    f16* vsave = (f16*)p; p += (size_t)AMB_CAP * 16 * DD / 2;
    float* dret = p; p += (size_t)AMB_CAP * DD;
    int* ambc = (int*)p; p += 64;
    int* ambgrow = (int*)p; p += AMB_CAP;
    float* scores = p;                      // [4096][2048]

    transpose_split<<<dim3(24, 24, 4), 256, 0, stream>>>(
        Wq, Wk, Wv, Wp, WQh, WQm, WKh, WKm, WVh, WPh, WkT32);
    zeroN<<<1, 64, 0, stream>>>(ambc);
    build_pooled_all<<<(BB * SS * DD) / 256, 256, 0, stream>>>(x, slots_all);

    // L0: producers for batch 0 + pm halves (k once; v pm into both bufs).
    megaSelProd<<<432, 256, 0, stream>>>(
        0, nullptr, nullptr, nullptr, 0, ambc, ambgrow, cand, oldw, vsave,
        1, 1, 1, x, slots_all, pm,
        WQh, WQm, WKh, WKm, WVh, bq, bk, bv, qh, qm, kh, km, v16a, v16b);
    // M0: scores(0).
    megaScoresProj<<<512, 256, 0, stream>>>(
        512, qh, qm, kh, km, scores, inv_sqrt_d, nullptr, WPh, bp, nullptr);

    for (int b = 1; b < BB; ++b) {
        f16* v16w = (b & 1) ? v16b : v16a;       // P(b) writes
        f16* v16r = ((b - 1) & 1) ? v16b : v16a; // C(b-1) reads
        f16* retrW = ((b - 1) & 1) ? retrB : retrA;

        // L(b): producers(b) tiles | select(b-1)
        megaSelProd<<<1312, 256, 0, stream>>>(
            1024, scores, v16r, retrW, (b - 1) * TT,
            ambc, ambgrow, cand, oldw, vsave,
            1, 1, 0, x + (size_t)b * TD, slots_all + (size_t)b * SD, nullptr,
            WQh, WQm, WKh, WKm, WVh, bq, bk, bv, qh, qm, kh, km, v16w, nullptr);
        // M(b): scores(b) | proj(b-1)
        megaScoresProj<<<704, 256, 0, stream>>>(
            512, qh, qm, kh, km, scores, inv_sqrt_d,
            retrW, WPh, bp, out + (size_t)(b - 1) * TD);
    }

    // L4: select(3) only.
    f16* v16r3 = v16b;           // (3&1) -> v16b
    f16* retrW3 = retrB;
    megaSelProd<<<1024, 256, 0, stream>>>(
        1024, scores, v16r3, retrW3, 3 * TT,
        ambc, ambgrow, cand, oldw, vsave,
        0, 0, 0, nullptr, nullptr, nullptr,
        WQh, WQm, WKh, WKm, WVh, bq, bk, bv, qh, qm, kh, km, nullptr, nullptr);
    // M4: proj(3) only.
    megaScoresProj<<<192, 256, 0, stream>>>(
        0, nullptr, nullptr, nullptr, nullptr, nullptr, 0.f,
        retrW3, WPh, bp, out + (size_t)3 * TD);

    // deferred exact fixups.
    fixA<<<dim3(12, AMB_CAP), 256, 0, stream>>>(ambc, ambgrow, x, Wq, bq, q64buf);
    fixB<<<dim3(12, AMB_CAP), 256, 0, stream>>>(ambc, WkT32, bk, q64buf, ubuf, bkqbuf);
    fixC<<<AMB_CAP, 256, 0, stream>>>(ambc, ambgrow, x, pm, cand, oldw,
                                      ubuf, bkqbuf, vsave, dret);
    fixD<<<dim3(12, AMB_CAP), 256, 0, stream>>>(ambc, ambgrow, dret, Wp, out);
}